// Round 15
// baseline (687.634 us; speedup 1.0000x reference)
//
#include <hip/hip_runtime.h>

// ---------------- types & helpers ----------------
typedef __bf16 bf16x8 __attribute__((ext_vector_type(8)));
typedef short  short8 __attribute__((ext_vector_type(8)));
typedef float  f32x4  __attribute__((ext_vector_type(4)));
typedef unsigned short u16;

#define NTOK 4096   // B*T
#define TSEQ 2048
#define CDIM 1024
#define NEXP 16

__device__ __forceinline__ u16 f2bf(float f){
  union { float f; unsigned u; } v; v.f = f;
  unsigned r = v.u + 0x7fffu + ((v.u >> 16) & 1u);
  return (u16)(r >> 16);
}

__device__ __forceinline__ f32x4 mfma16(short8 a, short8 b, f32x4 c){
  return __builtin_amdgcn_mfma_f32_16x16x32_bf16(
      __builtin_bit_cast(bf16x8, a), __builtin_bit_cast(bf16x8, b), c, 0, 0, 0);
}

__device__ __forceinline__ void gload_lds16(const void* g, void* l){
  __builtin_amdgcn_global_load_lds((__attribute__((address_space(1))) void*)g,
                                   (__attribute__((address_space(3))) void*)l,
                                   16, 0, 0);
}

// ---------------- transpose tile body (bit-identical output) ----------------
__device__ __forceinline__ void tp_body(const float* __restrict__ in, u16* __restrict__ out,
                                        int K, int N, int k0, int n0, u16* lds16, int tid)
{
  int tx = tid & 15;
#pragma unroll
  for (int p = 0; p < 2; ++p) {
    int q = (tid >> 4) + p * 16;
    int k = 2 * q;
    float4 v0 = *(const float4*)(in + (size_t)(k0 + k)     * N + n0 + tx * 4);
    float4 v1 = *(const float4*)(in + (size_t)(k0 + k + 1) * N + n0 + tx * 4);
    const float* a0 = (const float*)&v0;
    const float* a1 = (const float*)&v1;
#pragma unroll
    for (int i = 0; i < 4; ++i) {
      unsigned val = (unsigned)f2bf(a0[i]) | ((unsigned)f2bf(a1[i]) << 16);
      *(unsigned*)&lds16[(tx * 4 + i) * 66 + k] = val;
    }
  }
  __syncthreads();
#pragma unroll
  for (int p = 0; p < 2; ++p) {
    int n = (tid >> 3) + p * 32;
    int k8 = (tid & 7) * 8;
    const unsigned* l32 = (const unsigned*)&lds16[n * 66 + k8];
    uint4 o4;
    o4.x = l32[0]; o4.y = l32[1]; o4.z = l32[2]; o4.w = l32[3];
    *(uint4*)(out + (size_t)(n0 + n) * K + k0 + k8) = o4;
  }
}

// ---------------- early transpose: w_attn only ----------------
__global__ void transpose_wattn_k(const float* __restrict__ in, u16* __restrict__ out)
{
  __shared__ u16 lds16[64 * 66];
  int r = blockIdx.x;                     // 768 tiles: 48 n x 16 k
  int n0 = (r % 48) * 64, k0 = (r / 48) * 64;
  tp_body(in, out, 1024, 3072, k0, n0, lds16, threadIdx.x);
}

// ---------------- RMSNorm ----------------
__global__ void rmsnorm_k(const float* __restrict__ x, const float* __restrict__ w,
                          u16* __restrict__ ob, float* __restrict__ of)
{
  int row = blockIdx.x, tid = threadIdx.x;
  const float4* xr = (const float4*)(x + (size_t)row * CDIM);
  float4 v = xr[tid];
  float ss = v.x*v.x + v.y*v.y + v.z*v.z + v.w*v.w;
  for (int d = 1; d < 64; d <<= 1) ss += __shfl_xor(ss, d);
  __shared__ float wacc[4];
  if ((tid & 63) == 0) wacc[tid >> 6] = ss;
  __syncthreads();
  float tot = wacc[0] + wacc[1] + wacc[2] + wacc[3];
  float scale = rsqrtf(tot * (1.0f / CDIM) + 1e-5f);
  float4 wv = ((const float4*)w)[tid];
  float o0 = v.x * scale * wv.x, o1 = v.y * scale * wv.y;
  float o2 = v.z * scale * wv.z, o3 = v.w * scale * wv.w;
  if (of) ((float4*)(of + (size_t)row * CDIM))[tid] = make_float4(o0, o1, o2, o3);
  ushort4 ov; ov.x = f2bf(o0); ov.y = f2bf(o1); ov.z = f2bf(o2); ov.w = f2bf(o3);
  ((ushort4*)(ob + (size_t)row * CDIM))[tid] = ov;
}

// ---------------- GEMM: C[M,N] = A[M,K](bf16) @ Bt[N,K](bf16)^T + bias ----------------
// dbuf LDS + counted vmcnt + XCD-chunked swizzle (uniform per-chunk density only).
// MODE 0: f32 ; 1: f32+resid ; 2: bf16 silu ; 3: fused RoPE+split (qkv GEMM only,
//   N=3072: cols [0,1024)=q [1024,2048)=k [2048,3072)=v; per-element math verbatim
//   rope_split_k, partner value via shfl_xor(v,1) — bit-identical q/k/v).
template<int MODE>
__global__ void __launch_bounds__(256, 4)
gemm_bt(const u16* __restrict__ A, int lda,
        const u16* __restrict__ Bt, long long bStrideZ,
        const float* __restrict__ bias, int biasStrideZ,
        void* __restrict__ Cout,
        const float* __restrict__ resid,
        int M, int N, int K,
        const int* __restrict__ counts, const int* __restrict__ offsets,
        const int* __restrict__ tokA,
        u16* __restrict__ qr, u16* __restrict__ kr, u16* __restrict__ vtp)
{
  int nwg = gridDim.x * gridDim.y * gridDim.z;
  int d = (blockIdx.z * gridDim.y + blockIdx.y) * gridDim.x + blockIdx.x;
  int o = (d & 7) * (nwg >> 3) + (d >> 3);
  int cb = o % gridDim.x;
  int t2 = o / gridDim.x;
  int rb = t2 % gridDim.y;
  int z  = t2 / gridDim.y;

  int mLoc = M, rowBase = 0;
  if (counts) { mLoc = counts[z]; rowBase = offsets[z]; }
  if (rb * 128 >= mLoc) return;

  const u16* Bz = Bt + (size_t)z * bStrideZ;
  const float* bz = bias + (size_t)z * biasStrideZ;

  __shared__ u16 lds_a[2][128 * 32];
  __shared__ u16 lds_b[2][128 * 32];

  int tid = threadIdx.x;
  int lane = tid & 63, wave = tid >> 6;
  int wm = wave >> 1, wn = wave & 1;
  int srow = wave * 16 + (lane >> 2);
  int skel = (lane & 3) * 8;
  int r16 = lane & 15, g8 = (lane >> 4) * 8;

  size_t arow[2];
  int ncol[2];
#pragma unroll
  for (int c = 0; c < 2; ++c) {
    int rloc = rb * 128 + c * 64 + srow;
    if (rloc >= mLoc) rloc = mLoc - 1;
    int grow = rowBase + rloc;
    arow[c] = tokA ? (size_t)tokA[grow] : (size_t)grow;
    ncol[c] = cb * 128 + c * 64 + srow;
  }

  f32x4 acc[4][4] = {};

  auto stage = [&](int kt, int buf){
    int k0 = kt * 32;
#pragma unroll
    for (int c = 0; c < 2; ++c) {
      gload_lds16(A + arow[c] * lda + k0 + skel,
                  (char*)&lds_a[buf][0] + c * 4096 + wave * 1024);
      gload_lds16(Bz + (size_t)ncol[c] * K + k0 + skel,
                  (char*)&lds_b[buf][0] + c * 4096 + wave * 1024);
    }
  };

  int nkt = K >> 5;
  stage(0, 0);
  for (int kt = 0; kt < nkt; ++kt) {
    int buf = kt & 1;
    if (kt + 1 < nkt) {
      stage(kt + 1, buf ^ 1);
      asm volatile("s_waitcnt vmcnt(4)" ::: "memory");
    } else {
      asm volatile("s_waitcnt vmcnt(0)" ::: "memory");
    }
    __builtin_amdgcn_s_barrier();
    short8 af[4], bfr[4];
#pragma unroll
    for (int i = 0; i < 4; ++i) {
      af[i]  = *(const short8*)&lds_a[buf][(wm * 64 + i * 16 + r16) * 32 + g8];
      bfr[i] = *(const short8*)&lds_b[buf][(wn * 64 + i * 16 + r16) * 32 + g8];
    }
#pragma unroll
    for (int i = 0; i < 4; ++i)
#pragma unroll
      for (int j = 0; j < 4; ++j)
        acc[i][j] = mfma16(af[i], bfr[j], acc[i][j]);
    __builtin_amdgcn_s_barrier();
  }

  // epilogue: row = (lane>>4)*4 + r, col = lane&15
#pragma unroll
  for (int i = 0; i < 4; ++i) {
    int rl0 = rb * 128 + wm * 64 + i * 16 + (lane >> 4) * 4;
#pragma unroll
    for (int j = 0; j < 4; ++j) {
      int col = cb * 128 + wn * 64 + j * 16 + r16;
      float bv = bz[col];
#pragma unroll
      for (int r = 0; r < 4; ++r) {
        int rl = rl0 + r;
        if (rl >= mLoc) continue;       // uniform across lane pairs (same r) - shfl safe
        int grow = rowBase + rl;
        float v = acc[i][j][r] + bv;
        if (MODE == 0) {
          ((float*)Cout)[(size_t)grow * N + col] = v;
        } else if (MODE == 1) {
          ((float*)Cout)[(size_t)grow * N + col] = v + resid[(size_t)grow * N + col];
        } else if (MODE == 2) {
          float s = v * (1.0f / (1.0f + __expf(-v)));
          ((u16*)Cout)[(size_t)grow * N + col] = f2bf(s);
        } else {
          // fused RoPE+split (rope_split_k math verbatim; vp == partner's f32 qkv value)
          float vp = __shfl_xor(v, 1);
          int region = col >> 10;
          int c10 = col & 1023;
          int h = c10 >> 6, dd = c10 & 63;
          int b = grow >> 11, t = grow & 2047;
          int bh = b * 16 + h;
          if (region == 2) {
            vtp[((size_t)bh * 64 + dd) * TSEQ + t] = f2bf(v);
          } else {
            int i2 = dd >> 1;
            float freq = expf(-(float)i2 * (2.0f / 64.0f) * 9.210340371976184f);
            float ang = (float)t * freq;
            float sn, cs;
            sincosf(ang, &sn, &cs);
            float outv = (dd & 1) ? (vp * sn + v * cs) : (v * cs - vp * sn);
            u16* dst = (region == 0) ? qr : kr;
            dst[((size_t)bh * TSEQ + t) * 64 + dd] = f2bf(outv);
          }
        }
      }
    }
  }
}

// ---------------- FUSED: flash attention (512 blocks) + weight transposes (8832 blocks) ----------------
__global__ void __launch_bounds__(512, 4)
attn_tp_k(const u16* __restrict__ qr, const u16* __restrict__ kr,
          const u16* __restrict__ vt, u16* __restrict__ y,
          const float* __restrict__ wProj, const float* __restrict__ shWf,
          const float* __restrict__ shWp,  const float* __restrict__ expWf,
          const float* __restrict__ expWp,
          u16* __restrict__ oProj, u16* __restrict__ oWf17, u16* __restrict__ oWp17)
{
  __shared__ union {
    struct { u16 lK[2][64 * 64]; u16 lV[2][64 * 64]; u16 plds[8][16 * 72]; } a;  // 51200 B
    u16 t[2][64 * 66];                                                            // 16896 B
  } sm;

  int u = blockIdx.x;
  if (u >= 512) {
    int tid = threadIdx.x;
    int half = tid >> 8, t256 = tid & 255;
    int t = (u - 512) * 2 + half;          // 0..17663
    const float* in; u16* out; int K, N, k0, n0;
    if (t < 8192) {                        // exp_wf
      int z = t >> 9, r = t & 511;
      in = expWf + (size_t)z * 2048 * 1024; out = oWf17 + (size_t)z * 2048 * 1024;
      K = 1024; N = 2048; n0 = (r & 31) * 64; k0 = (r >> 5) * 64;
    } else if (t < 16384) {                // exp_wp
      int z = (t - 8192) >> 9, r = (t - 8192) & 511;
      in = expWp + (size_t)z * 2048 * 1024; out = oWp17 + (size_t)z * 2048 * 1024;
      K = 2048; N = 1024; n0 = (r & 15) * 64; k0 = (r >> 4) * 64;
    } else if (t < 16896) {                // sh_wf -> slot 16
      int r = t - 16384;
      in = shWf; out = oWf17 + (size_t)16 * 2048 * 1024;
      K = 1024; N = 2048; n0 = (r & 31) * 64; k0 = (r >> 5) * 64;
    } else if (t < 17408) {                // sh_wp -> slot 16
      int r = t - 16896;
      in = shWp; out = oWp17 + (size_t)16 * 2048 * 1024;
      K = 2048; N = 1024; n0 = (r & 15) * 64; k0 = (r >> 4) * 64;
    } else {                               // w_proj
      int r = t - 17408;
      in = wProj; out = oProj; K = 1024; N = 1024; n0 = (r & 15) * 64; k0 = (r >> 4) * 64;
    }
    tp_body(in, out, K, N, k0, n0, &sm.t[half][0], t256);
    return;
  }

  // ---- attention branch (R7-exact) ----
  int bh = u >> 4;
  int b = bh >> 4, h = bh & 15;
  int qb = 15 - (u & 15);                  // LPT
  int tid = threadIdx.x;
  int wv = tid >> 6, lane = tid & 63;
  int qrow0 = qb * 128 + wv * 16;
  const u16* qbase = qr + (size_t)bh * TSEQ * 64;
  const u16* kbase = kr + (size_t)bh * TSEQ * 64;
  const u16* vbase = vt + (size_t)bh * 64 * TSEQ;

  u16* pw = &sm.a.plds[wv][0];

  int r16 = lane & 15, g = lane >> 4;

  short8 aq0 = *(const short8*)(qbase + (size_t)(qrow0 + r16) * 64 + g * 8);
  short8 aq1 = *(const short8*)(qbase + (size_t)(qrow0 + r16) * 64 + 32 + g * 8);

  int sRow = tid >> 3;
  int sColE = (((tid & 7) * 16) ^ ((sRow & 7) << 4)) >> 1;

  float m[4] = {-1e30f, -1e30f, -1e30f, -1e30f};
  float l[4] = {0.f, 0.f, 0.f, 0.f};
  f32x4 o[4] = {};

  int nt = 2 * qb + 2;

  auto stage = [&](int t, int buf){
    int kp = t * 64;
    gload_lds16(kbase + ((size_t)(kp + sRow) << 6) + sColE,
                (char*)&sm.a.lK[buf][0] + wv * 1024);
    gload_lds16(vbase + (size_t)sRow * TSEQ + kp + sColE,
                (char*)&sm.a.lV[buf][0] + wv * 1024);
  };

  auto compute = [&](int t, int buf){
    int kp = t * 64;
    f32x4 s[4];
    __builtin_amdgcn_s_setprio(1);
#pragma unroll
    for (int st = 0; st < 4; ++st) {
      int rowK = st * 16 + r16;
      int sw = (rowK & 7) << 4;
      short8 kb0 = *(const short8*)((const char*)&sm.a.lK[buf][0] + rowK * 128 + ((g * 16) ^ sw));
      short8 kb1 = *(const short8*)((const char*)&sm.a.lK[buf][0] + rowK * 128 + ((64 + g * 16) ^ sw));
      f32x4 acc = {0.f, 0.f, 0.f, 0.f};
      acc = mfma16(aq0, kb0, acc);
      acc = mfma16(aq1, kb1, acc);
      s[st] = acc;
    }
    __builtin_amdgcn_s_setprio(0);

    float sc[4];
#pragma unroll
    for (int r = 0; r < 4; ++r) {
      int qpos = qrow0 + g * 4 + r;
      float v0 = (kp + r16      <= qpos) ? s[0][r] * 0.125f : -1e30f;
      float v1 = (kp + 16 + r16 <= qpos) ? s[1][r] * 0.125f : -1e30f;
      float v2 = (kp + 32 + r16 <= qpos) ? s[2][r] * 0.125f : -1e30f;
      float v3 = (kp + 48 + r16 <= qpos) ? s[3][r] * 0.125f : -1e30f;
      float mx = fmaxf(fmaxf(v0, v1), fmaxf(v2, v3));
      for (int d = 1; d < 16; d <<= 1) mx = fmaxf(mx, __shfl_xor(mx, d));
      float mnew = fmaxf(m[r], mx);
      float e0 = __expf(v0 - mnew), e1 = __expf(v1 - mnew);
      float e2 = __expf(v2 - mnew), e3 = __expf(v3 - mnew);
      float scale = __expf(m[r] - mnew);
      float rs = (e0 + e1) + (e2 + e3);
      for (int d = 1; d < 16; d <<= 1) rs += __shfl_xor(rs, d);
      l[r] = l[r] * scale + rs;
      m[r] = mnew;
      sc[r] = scale;
      int prow = (g * 4 + r) * 72;
      pw[prow + r16]      = f2bf(e0);
      pw[prow + 16 + r16] = f2bf(e1);
      pw[prow + 32 + r16] = f2bf(e2);
      pw[prow + 48 + r16] = f2bf(e3);
    }
#pragma unroll
    for (int c = 0; c < 4; ++c) {
      f32x4 t4 = o[c];
      t4[0] *= sc[0]; t4[1] *= sc[1]; t4[2] *= sc[2]; t4[3] *= sc[3];
      o[c] = t4;
    }

    short8 pa0 = *(const short8*)&pw[r16 * 72 + g * 8];
    short8 pa1 = *(const short8*)&pw[r16 * 72 + 32 + g * 8];
    __builtin_amdgcn_s_setprio(1);
#pragma unroll
    for (int c = 0; c < 4; ++c) {
      int rowV = c * 16 + r16;
      int sw = (rowV & 7) << 4;
      short8 vb0 = *(const short8*)((const char*)&sm.a.lV[buf][0] + rowV * 128 + ((g * 16) ^ sw));
      short8 vb1 = *(const short8*)((const char*)&sm.a.lV[buf][0] + rowV * 128 + ((64 + g * 16) ^ sw));
      o[c] = mfma16(pa0, vb0, o[c]);
      o[c] = mfma16(pa1, vb1, o[c]);
    }
    __builtin_amdgcn_s_setprio(0);
  };

  stage(0, 0);
  for (int t = 0; t < nt; ++t) {
    int buf = t & 1;
    if (t + 1 < nt) {
      stage(t + 1, buf ^ 1);
      asm volatile("s_waitcnt vmcnt(2)" ::: "memory");
    } else {
      asm volatile("s_waitcnt vmcnt(0)" ::: "memory");
    }
    __builtin_amdgcn_s_barrier();
    compute(t, buf);
    __builtin_amdgcn_s_barrier();
  }

#pragma unroll
  for (int c = 0; c < 4; ++c)
#pragma unroll
    for (int r = 0; r < 4; ++r) {
      int qpos = qrow0 + g * 4 + r;
      float val = o[c][r] / l[r];
      y[((size_t)(b * TSEQ + qpos)) * CDIM + h * 64 + c * 16 + r16] = f2bf(val);
    }
}

// ---------------- MoE routing ----------------
__global__ void zero_k(int* counts){
  int t = threadIdx.x;
  if (t < NEXP) counts[t] = 0;
}

__global__ void gate_k(const float* __restrict__ h2, const float* __restrict__ gw,
                       const float* __restrict__ gb,
                       int* __restrict__ route_e, float* __restrict__ route_w,
                       int* __restrict__ counts, float* __restrict__ probs)
{
  int n = blockIdx.x, tid = threadIdx.x;
  __shared__ float hrow[CDIM];
  __shared__ float part[16][17];
  __shared__ float sm[16];
  ((float4*)hrow)[tid] = ((const float4*)(h2 + (size_t)n * CDIM))[tid];
  __syncthreads();
  int e = tid & 15, seg = tid >> 4;
  const float4* gw4 = (const float4*)(gw + (size_t)e * CDIM + seg * 64);
  const float4* hs4 = (const float4*)(hrow + seg * 64);
  float p = 0.f;
#pragma unroll
  for (int i = 0; i < 16; ++i) {
    float4 gv = gw4[i];
    float4 hv = hs4[i];
    p += hv.x * gv.x;
    p += hv.y * gv.y;
    p += hv.z * gv.z;
    p += hv.w * gv.w;
  }
  part[e][seg] = p;
  __syncthreads();
  if (tid < 16) {
    float lg = 0.f;
    for (int s = 0; s < 16; ++s) lg += part[tid][s];
    sm[tid] = lg;
  }
  __syncthreads();
  if (tid == 0) {
    float mx = sm[0];
    for (int i = 1; i < 16; ++i) mx = fmaxf(mx, sm[i]);
    float ssum = 0.f;
    for (int i = 0; i < 16; ++i) { float pe = expf(sm[i] - mx); sm[i] = pe; ssum += pe; }
    float inv = 1.0f / ssum;
    for (int i = 0; i < 16; ++i) sm[i] *= inv;
    int i1 = -1; float b1 = -1e30f;
    for (int i = 0; i < 16; ++i) { float t = sm[i] + gb[i]; if (t > b1) { b1 = t; i1 = i; } }
    int i2 = -1; float b2 = -1e30f;
    for (int i = 0; i < 16; ++i) { if (i == i1) continue; float t = sm[i] + gb[i]; if (t > b2) { b2 = t; i2 = i; } }
    route_e[2 * n] = i1; route_e[2 * n + 1] = i2;
    route_w[2 * n] = sm[i1]; route_w[2 * n + 1] = sm[i2];
    atomicAdd(&counts[i1], 1); atomicAdd(&counts[i2], 1);
  }
  __syncthreads();
  if (tid < 16) probs[(size_t)n * 16 + tid] = sm[tid];
}

__global__ void scan_k(const int* counts, int* offs, int* cursors){
  if (threadIdx.x == 0) {
    int acc = 0;
    for (int e = 0; e < NEXP; ++e) { offs[e] = acc; cursors[e] = acc; acc += counts[e]; }
    offs[NEXP] = acc;
  }
}

__global__ void fill_k(const int* __restrict__ route_e, const float* __restrict__ route_w,
                       int* __restrict__ cursors, int* __restrict__ tok, float* __restrict__ tw,
                       int* __restrict__ inv)
{
  int n = blockIdx.x * 256 + threadIdx.x;
  if (n >= NTOK) return;
  for (int j = 0; j < 2; ++j) {
    int e = route_e[2 * n + j];
    int pos = atomicAdd(&cursors[e], 1);
    tok[pos] = n; tw[pos] = route_w[2 * n + j];
    inv[2 * n + j] = pos;
  }
}

// out[n] += eout[p0]*w0 + eout[p1]*w1   (eout f32)
__global__ void combine_k(float* __restrict__ out, const float* __restrict__ eout,
                          const int* __restrict__ inv, const float* __restrict__ tw)
{
  int n = blockIdx.x, tid = threadIdx.x;
  int p0 = inv[2 * n], p1 = inv[2 * n + 1];
  float w0 = tw[p0], w1 = tw[p1];
  float4 a  = ((float4*)(out + (size_t)n * CDIM))[tid];
  float4 e0 = ((const float4*)(eout + (size_t)p0 * CDIM))[tid];
  float4 e1 = ((const float4*)(eout + (size_t)p1 * CDIM))[tid];
  a.x += e0.x * w0 + e1.x * w1;
  a.y += e0.y * w0 + e1.y * w1;
  a.z += e0.z * w0 + e1.z * w1;
  a.w += e0.w * w0 + e1.w * w1;
  ((float4*)(out + (size_t)n * CDIM))[tid] = a;
}

// deterministic psum reduction + lb loss
__global__ void lb2_k(const int* __restrict__ counts, const float* __restrict__ probs,
                      float* __restrict__ out)
{
  __shared__ float part[256][16];
  int t = threadIdx.x;
  float acc[16];
#pragma unroll
  for (int e = 0; e < 16; ++e) acc[e] = 0.f;
  for (int n = t; n < NTOK; n += 256) {
    const float4* row = (const float4*)(probs + (size_t)n * 16);
    float4 a0 = row[0], a1 = row[1], a2 = row[2], a3 = row[3];
    acc[0] += a0.x; acc[1] += a0.y; acc[2]  += a0.z; acc[3]  += a0.w;
    acc[4] += a1.x; acc[5] += a1.y; acc[6]  += a1.z; acc[7]  += a1.w;
    acc[8] += a2.x; acc[9] += a2.y; acc[10] += a2.z; acc[11] += a2.w;
    acc[12] += a3.x; acc[13] += a3.y; acc[14] += a3.z; acc[15] += a3.w;
  }
#pragma unroll
  for (int e = 0; e < 16; ++e) part[t][e] = acc[e];
  __syncthreads();
  __shared__ float colsum[16];
  if (t < 16) {
    float s = 0.f;
    for (int i = 0; i < 256; ++i) s += part[i][t];
    colsum[t] = s;
  }
  __syncthreads();
  if (t == 0) {
    float accl = 0.f;
    for (int e = 0; e < NEXP; ++e) {
      float f = (float)counts[e] * (16.0f / (2.0f * (float)NTOK + 1e-6f));
      accl += f * (colsum[e] * (1.0f / (float)NTOK));
    }
    out[0] = 0.01f * accl;
  }
}

// ---------------- launch ----------------
extern "C" void kernel_launch(void* const* d_in, const int* in_sizes, int n_in,
                              void* d_out, int out_size, void* d_ws, size_t ws_size,
                              hipStream_t stream)
{
  const float* x      = (const float*)d_in[0];
  const float* ln1_w  = (const float*)d_in[1];
  const float* ln2_w  = (const float*)d_in[2];
  const float* w_attn = (const float*)d_in[3];
  const float* b_attn = (const float*)d_in[4];
  const float* w_proj = (const float*)d_in[5];
  const float* b_proj = (const float*)d_in[6];
  const float* gate_w = (const float*)d_in[7];
  const float* gate_b = (const float*)d_in[8];
  const float* exp_wf = (const float*)d_in[9];
  const float* exp_bf = (const float*)d_in[10];
  const float* exp_wp = (const float*)d_in[11];
  const float* exp_bp = (const float*)d_in[12];
  const float* sh_wf  = (const float*)d_in[13];
  const float* sh_bf  = (const float*)d_in[14];
  const float* sh_wp  = (const float*)d_in[15];
  const float* sh_bp  = (const float*)d_in[16];

  char* ws = (char*)d_ws;
  size_t off = 0;
  auto alloc = [&](size_t b){ size_t r = off; off = (off + b + 255) & ~(size_t)255; return r; };

  size_t oWAttnT = alloc(3072ull * 1024 * 2);
  size_t oWProjT = alloc(1024ull * 1024 * 2);
  size_t oExpWfT = alloc(17ull * 2048 * 1024 * 2);   // slot 16 = sh_wf
  size_t oExpWpT = alloc(17ull * 1024 * 2048 * 2);   // slot 16 = sh_wp
  size_t oX2     = alloc(4096ull * 1024 * 4);
  size_t oH2F    = alloc(4096ull * 2048 * 2);   // h2 f32 16MB; later hid_sh bf16
  size_t oH2B    = alloc(4096ull * 1024 * 2);
  size_t oHidMoe = alloc(8192ull * 2048 * 2);   // hid_moe bf16 32MB
  size_t oQR     = alloc(4096ull * 1024 * 2);   // QR+KR+VT+H1B = 32MB; later eout f32 [8192][1024]
  size_t oKR     = alloc(4096ull * 1024 * 2);
  size_t oVT     = alloc(4096ull * 1024 * 2);
  size_t oH1B    = alloc(4096ull * 1024 * 2);
  size_t oCnt    = alloc(128);
  size_t oOffs   = alloc(128);
  size_t oCurs   = alloc(128);
  size_t oRE     = alloc(8192ull * 4);
  size_t oRW     = alloc(8192ull * 4);
  size_t oTok    = alloc(8192ull * 4);
  size_t oTw     = alloc(8192ull * 4);
  size_t oInv    = alloc(8192ull * 4);
  size_t oProbs  = alloc(4096ull * 16 * 4);
  size_t oY      = alloc(4096ull * 1024 * 2);   // y bf16 (h1 slot reused below is fine too)

  u16* pWAttnT = (u16*)(ws + oWAttnT);
  u16* pWProjT = (u16*)(ws + oWProjT);
  u16* pWf17   = (u16*)(ws + oExpWfT);
  u16* pWp17   = (u16*)(ws + oExpWpT);
  float* pX2   = (float*)(ws + oX2);
  float* pH2F  = (float*)(ws + oH2F);
  u16* pHidSh  = (u16*)(ws + oH2F);             // alias (h2f dead after gate_k)
  u16* pH2B    = (u16*)(ws + oH2B);
  u16* pHidMoe = (u16*)(ws + oHidMoe);
  u16* pQR     = (u16*)(ws + oQR);
  u16* pKR     = (u16*)(ws + oKR);
  u16* pVT     = (u16*)(ws + oVT);
  u16* pH1B    = (u16*)(ws + oH1B);
  float* pEout = (float*)(ws + oQR);            // alias (qr/kr/vt/h1 dead after proj), 32MB
  u16* pY      = (u16*)(ws + oY);
  int* pCnt    = (int*)(ws + oCnt);
  int* pOffs   = (int*)(ws + oOffs);
  int* pCurs   = (int*)(ws + oCurs);
  int* pRE     = (int*)(ws + oRE);
  float* pRW   = (float*)(ws + oRW);
  int* pTok    = (int*)(ws + oTok);
  float* pTw   = (float*)(ws + oTw);
  int* pInv    = (int*)(ws + oInv);
  float* pProbs= (float*)(ws + oProbs);

  // 1) early transpose: w_attn only
  transpose_wattn_k<<<768, 256, 0, stream>>>(w_attn, pWAttnT);

  // 2) rmsnorm1 -> h1 bf16
  rmsnorm_k<<<NTOK, 256, 0, stream>>>(x, ln1_w, pH1B, nullptr);

  // 3) qkv GEMM with fused RoPE+split -> qr, kr, vt directly (no f32 qkv roundtrip)
  gemm_bt<3><<<dim3(3072/128, NTOK/128, 1), 256, 0, stream>>>(
      pH1B, 1024, pWAttnT, 0, b_attn, 0, nullptr, nullptr,
      NTOK, 3072, 1024, nullptr, nullptr, nullptr, pQR, pKR, pVT);

  // 4) FUSED: causal flash attention + remaining weight transposes
  attn_tp_k<<<512 + 8832, 512, 0, stream>>>(pQR, pKR, pVT, pY,
                                            w_proj, sh_wf, sh_wp, exp_wf, exp_wp,
                                            pWProjT, pWf17, pWp17);

  // 5) x2 = x + y @ w_proj + b_proj
  gemm_bt<1><<<dim3(1024/128, NTOK/128, 1), 256, 0, stream>>>(
      pY, 1024, pWProjT, 0, b_proj, 0, pX2, x,
      NTOK, 1024, 1024, nullptr, nullptr, nullptr, nullptr, nullptr, nullptr);

  // 6) rmsnorm2 -> h2 bf16 + f32
  rmsnorm_k<<<NTOK, 256, 0, stream>>>(pX2, ln2_w, pH2B, pH2F);

  // 7) routing
  zero_k<<<1, 64, 0, stream>>>(pCnt);
  gate_k<<<NTOK, 256, 0, stream>>>(pH2F, gate_w, gate_b, pRE, pRW, pCnt, pProbs);
  scan_k<<<1, 64, 0, stream>>>(pCnt, pOffs, pCurs);
  fill_k<<<NTOK/256, 256, 0, stream>>>(pRE, pRW, pCurs, pTok, pTw, pInv);
  lb2_k<<<1, 256, 0, stream>>>(pCnt, pProbs, ((float*)d_out) + (size_t)NTOK * CDIM);

  // 8) shared MLP: hid_sh = silu(h2 @ sh_wf + sh_bf)   (slot 16 of wf17)
  gemm_bt<2><<<dim3(2048/128, NTOK/128, 1), 256, 0, stream>>>(
      pH2B, 1024, pWf17 + (size_t)16 * 2048 * 1024, 0, sh_bf, 0, pHidSh, nullptr,
      NTOK, 2048, 1024, nullptr, nullptr, nullptr, nullptr, nullptr, nullptr);

  // 9) d_out = x2 + hid_sh @ sh_wp + sh_bp   (slot 16 of wp17)
  gemm_bt<1><<<dim3(1024/128, NTOK/128, 1), 256, 0, stream>>>(
      pHidSh, 2048, pWp17 + (size_t)16 * 2048 * 1024, 0, sh_bp, 0, (float*)d_out, pX2,
      NTOK, 1024, 2048, nullptr, nullptr, nullptr, nullptr, nullptr, nullptr);

  // 10) experts ff: hid_moe = silu(h2b[tok] @ wf_e + bf_e)
  gemm_bt<2><<<dim3(2048/128, NTOK/128, 16), 256, 0, stream>>>(
      pH2B, 1024, pWf17, 2048ll * 1024, exp_bf, 2048, pHidMoe, nullptr,
      NTOK, 2048, 1024, pCnt, pOffs, pTok, nullptr, nullptr, nullptr);

  // 11) experts proj -> eout f32
  gemm_bt<0><<<dim3(1024/128, NTOK/128, 16), 256, 0, stream>>>(
      pHidMoe, 2048, pWp17, 2048ll * 1024, exp_bp, 1024, pEout, nullptr,
      NTOK, 1024, 2048, pCnt, pOffs, nullptr, nullptr, nullptr, nullptr);

  // 12) d_out += eout[pos0]*w0 + eout[pos1]*w1
  combine_k<<<NTOK, 256, 0, stream>>>((float*)d_out, pEout, pInv, pTw);

  (void)in_sizes; (void)n_in; (void)out_size; (void)ws_size;
}

// Round 16
// 672.234 us; speedup vs baseline: 1.0229x; 1.0229x over previous
//
#include <hip/hip_runtime.h>

// ---------------- types & helpers ----------------
typedef __bf16 bf16x8 __attribute__((ext_vector_type(8)));
typedef short  short8 __attribute__((ext_vector_type(8)));
typedef float  f32x4  __attribute__((ext_vector_type(4)));
typedef unsigned short u16;

#define NTOK 4096   // B*T
#define TSEQ 2048
#define CDIM 1024
#define NEXP 16

__device__ __forceinline__ u16 f2bf(float f){
  union { float f; unsigned u; } v; v.f = f;
  unsigned r = v.u + 0x7fffu + ((v.u >> 16) & 1u);
  return (u16)(r >> 16);
}
__device__ __forceinline__ float bf2f(u16 u){
  union { unsigned u; float f; } v; v.u = ((unsigned)u) << 16; return v.f;
}

__device__ __forceinline__ f32x4 mfma16(short8 a, short8 b, f32x4 c){
  return __builtin_amdgcn_mfma_f32_16x16x32_bf16(
      __builtin_bit_cast(bf16x8, a), __builtin_bit_cast(bf16x8, b), c, 0, 0, 0);
}

__device__ __forceinline__ void gload_lds16(const void* g, void* l){
  __builtin_amdgcn_global_load_lds((__attribute__((address_space(1))) void*)g,
                                   (__attribute__((address_space(3))) void*)l,
                                   16, 0, 0);
}

// ---------------- transpose tile body (bit-identical output) ----------------
__device__ __forceinline__ void tp_body(const float* __restrict__ in, u16* __restrict__ out,
                                        int K, int N, int k0, int n0, u16* lds16, int tid)
{
  int tx = tid & 15;
#pragma unroll
  for (int p = 0; p < 2; ++p) {
    int q = (tid >> 4) + p * 16;
    int k = 2 * q;
    float4 v0 = *(const float4*)(in + (size_t)(k0 + k)     * N + n0 + tx * 4);
    float4 v1 = *(const float4*)(in + (size_t)(k0 + k + 1) * N + n0 + tx * 4);
    const float* a0 = (const float*)&v0;
    const float* a1 = (const float*)&v1;
#pragma unroll
    for (int i = 0; i < 4; ++i) {
      unsigned val = (unsigned)f2bf(a0[i]) | ((unsigned)f2bf(a1[i]) << 16);
      *(unsigned*)&lds16[(tx * 4 + i) * 66 + k] = val;
    }
  }
  __syncthreads();
#pragma unroll
  for (int p = 0; p < 2; ++p) {
    int n = (tid >> 3) + p * 32;
    int k8 = (tid & 7) * 8;
    const unsigned* l32 = (const unsigned*)&lds16[n * 66 + k8];
    uint4 o4;
    o4.x = l32[0]; o4.y = l32[1]; o4.z = l32[2]; o4.w = l32[3];
    *(uint4*)(out + (size_t)(n0 + n) * K + k0 + k8) = o4;
  }
}

// ---------------- early transpose: w_attn only ----------------
__global__ void transpose_wattn_k(const float* __restrict__ in, u16* __restrict__ out)
{
  __shared__ u16 lds16[64 * 66];
  int r = blockIdx.x;                     // 768 tiles: 48 n x 16 k
  int n0 = (r % 48) * 64, k0 = (r / 48) * 64;
  tp_body(in, out, 1024, 3072, k0, n0, lds16, threadIdx.x);
}

// ---------------- RMSNorm ----------------
__global__ void rmsnorm_k(const float* __restrict__ x, const float* __restrict__ w,
                          u16* __restrict__ ob, float* __restrict__ of)
{
  int row = blockIdx.x, tid = threadIdx.x;
  const float4* xr = (const float4*)(x + (size_t)row * CDIM);
  float4 v = xr[tid];
  float ss = v.x*v.x + v.y*v.y + v.z*v.z + v.w*v.w;
  for (int d = 1; d < 64; d <<= 1) ss += __shfl_xor(ss, d);
  __shared__ float wacc[4];
  if ((tid & 63) == 0) wacc[tid >> 6] = ss;
  __syncthreads();
  float tot = wacc[0] + wacc[1] + wacc[2] + wacc[3];
  float scale = rsqrtf(tot * (1.0f / CDIM) + 1e-5f);
  float4 wv = ((const float4*)w)[tid];
  float o0 = v.x * scale * wv.x, o1 = v.y * scale * wv.y;
  float o2 = v.z * scale * wv.z, o3 = v.w * scale * wv.w;
  if (of) ((float4*)(of + (size_t)row * CDIM))[tid] = make_float4(o0, o1, o2, o3);
  ushort4 ov; ov.x = f2bf(o0); ov.y = f2bf(o1); ov.z = f2bf(o2); ov.w = f2bf(o3);
  ((ushort4*)(ob + (size_t)row * CDIM))[tid] = ov;
}

// ---------------- GEMM: C[M,N] = A[M,K](bf16) @ Bt[N,K](bf16)^T + bias ----------------
// dbuf LDS + counted vmcnt + XCD-chunked swizzle (uniform per-chunk density only).
// MODE 0: f32 ; 1: f32+resid ; 2: bf16 silu ; 4: bf16 plain
template<int MODE>
__global__ void __launch_bounds__(256, 4)
gemm_bt(const u16* __restrict__ A, int lda,
        const u16* __restrict__ Bt, long long bStrideZ,
        const float* __restrict__ bias, int biasStrideZ,
        void* __restrict__ Cout,
        const float* __restrict__ resid,
        int M, int N, int K,
        const int* __restrict__ counts, const int* __restrict__ offsets,
        const int* __restrict__ tokA)
{
  int nwg = gridDim.x * gridDim.y * gridDim.z;
  int d = (blockIdx.z * gridDim.y + blockIdx.y) * gridDim.x + blockIdx.x;
  int o = (d & 7) * (nwg >> 3) + (d >> 3);
  int cb = o % gridDim.x;
  int t2 = o / gridDim.x;
  int rb = t2 % gridDim.y;
  int z  = t2 / gridDim.y;

  int mLoc = M, rowBase = 0;
  if (counts) { mLoc = counts[z]; rowBase = offsets[z]; }
  if (rb * 128 >= mLoc) return;

  const u16* Bz = Bt + (size_t)z * bStrideZ;
  const float* bz = bias + (size_t)z * biasStrideZ;

  __shared__ u16 lds_a[2][128 * 32];
  __shared__ u16 lds_b[2][128 * 32];

  int tid = threadIdx.x;
  int lane = tid & 63, wave = tid >> 6;
  int wm = wave >> 1, wn = wave & 1;
  int srow = wave * 16 + (lane >> 2);
  int skel = (lane & 3) * 8;
  int r16 = lane & 15, g8 = (lane >> 4) * 8;

  size_t arow[2];
  int ncol[2];
#pragma unroll
  for (int c = 0; c < 2; ++c) {
    int rloc = rb * 128 + c * 64 + srow;
    if (rloc >= mLoc) rloc = mLoc - 1;
    int grow = rowBase + rloc;
    arow[c] = tokA ? (size_t)tokA[grow] : (size_t)grow;
    ncol[c] = cb * 128 + c * 64 + srow;
  }

  f32x4 acc[4][4] = {};

  auto stage = [&](int kt, int buf){
    int k0 = kt * 32;
#pragma unroll
    for (int c = 0; c < 2; ++c) {
      gload_lds16(A + arow[c] * lda + k0 + skel,
                  (char*)&lds_a[buf][0] + c * 4096 + wave * 1024);
      gload_lds16(Bz + (size_t)ncol[c] * K + k0 + skel,
                  (char*)&lds_b[buf][0] + c * 4096 + wave * 1024);
    }
  };

  int nkt = K >> 5;
  stage(0, 0);
  for (int kt = 0; kt < nkt; ++kt) {
    int buf = kt & 1;
    if (kt + 1 < nkt) {
      stage(kt + 1, buf ^ 1);
      asm volatile("s_waitcnt vmcnt(4)" ::: "memory");
    } else {
      asm volatile("s_waitcnt vmcnt(0)" ::: "memory");
    }
    __builtin_amdgcn_s_barrier();
    short8 af[4], bfr[4];
#pragma unroll
    for (int i = 0; i < 4; ++i) {
      af[i]  = *(const short8*)&lds_a[buf][(wm * 64 + i * 16 + r16) * 32 + g8];
      bfr[i] = *(const short8*)&lds_b[buf][(wn * 64 + i * 16 + r16) * 32 + g8];
    }
#pragma unroll
    for (int i = 0; i < 4; ++i)
#pragma unroll
      for (int j = 0; j < 4; ++j)
        acc[i][j] = mfma16(af[i], bfr[j], acc[i][j]);
    __builtin_amdgcn_s_barrier();
  }

  // epilogue: row = (lane>>4)*4 + r, col = lane&15
#pragma unroll
  for (int i = 0; i < 4; ++i) {
    int rl0 = rb * 128 + wm * 64 + i * 16 + (lane >> 4) * 4;
#pragma unroll
    for (int j = 0; j < 4; ++j) {
      int col = cb * 128 + wn * 64 + j * 16 + r16;
      float bv = bz[col];
#pragma unroll
      for (int r = 0; r < 4; ++r) {
        int rl = rl0 + r;
        if (rl >= mLoc) continue;
        int grow = rowBase + rl;
        float v = acc[i][j][r] + bv;
        if (MODE == 0) {
          ((float*)Cout)[(size_t)grow * N + col] = v;
        } else if (MODE == 1) {
          ((float*)Cout)[(size_t)grow * N + col] = v + resid[(size_t)grow * N + col];
        } else if (MODE == 2) {
          float s = v * (1.0f / (1.0f + __expf(-v)));
          ((u16*)Cout)[(size_t)grow * N + col] = f2bf(s);
        } else {
          ((u16*)Cout)[(size_t)grow * N + col] = f2bf(v);
        }
      }
    }
  }
}

// ---------------- RoPE + split: qkv f32 -> q,k [BH][T][D] bf16, v^T [BH][D][T] bf16 ----------------
__global__ void rope_split_k(const float* __restrict__ qkv,
                             u16* __restrict__ qr, u16* __restrict__ kr,
                             u16* __restrict__ vt)
{
  int flat = blockIdx.x * 256 + threadIdx.x;
  int i = flat & 31;
  int h = (flat >> 5) & 15;
  int n = flat >> 9;
  int b = n >> 11, t = n & 2047;
  const float* row = qkv + (size_t)n * 3072;
  float2 q = *(const float2*)(row + h * 64 + 2 * i);
  float2 k = *(const float2*)(row + 1024 + h * 64 + 2 * i);
  float2 v = *(const float2*)(row + 2048 + h * 64 + 2 * i);
  float freq = expf(-(float)i * (2.0f / 64.0f) * 9.210340371976184f);
  float ang = (float)t * freq;
  float sn, cs;
  sincosf(ang, &sn, &cs);
  float q0 = q.x * cs - q.y * sn, q1 = q.x * sn + q.y * cs;
  float k0 = k.x * cs - k.y * sn, k1 = k.x * sn + k.y * cs;
  int bh = b * 16 + h;
  size_t qoff = ((size_t)bh * TSEQ + t) * 64 + 2 * i;
  *(unsigned*)(qr + qoff) = (unsigned)f2bf(q0) | ((unsigned)f2bf(q1) << 16);
  *(unsigned*)(kr + qoff) = (unsigned)f2bf(k0) | ((unsigned)f2bf(k1) << 16);
  size_t voff = ((size_t)bh * 64 + 2 * i) * TSEQ + t;
  vt[voff] = f2bf(v.x);
  vt[voff + TSEQ] = f2bf(v.y);
}

// ---------------- FUSED: flash attention (512 blocks) + weight transposes (8832 blocks) ----------------
__global__ void __launch_bounds__(512, 4)
attn_tp_k(const u16* __restrict__ qr, const u16* __restrict__ kr,
          const u16* __restrict__ vt, u16* __restrict__ y,
          const float* __restrict__ wProj, const float* __restrict__ shWf,
          const float* __restrict__ shWp,  const float* __restrict__ expWf,
          const float* __restrict__ expWp,
          u16* __restrict__ oProj, u16* __restrict__ oWf17, u16* __restrict__ oWp17)
{
  __shared__ union {
    struct { u16 lK[2][64 * 64]; u16 lV[2][64 * 64]; u16 plds[8][16 * 72]; } a;  // 51200 B
    u16 t[2][64 * 66];                                                            // 16896 B
  } sm;

  int u = blockIdx.x;
  if (u >= 512) {
    int tid = threadIdx.x;
    int half = tid >> 8, t256 = tid & 255;
    int t = (u - 512) * 2 + half;          // 0..17663
    const float* in; u16* out; int K, N, k0, n0;
    if (t < 8192) {                        // exp_wf
      int z = t >> 9, r = t & 511;
      in = expWf + (size_t)z * 2048 * 1024; out = oWf17 + (size_t)z * 2048 * 1024;
      K = 1024; N = 2048; n0 = (r & 31) * 64; k0 = (r >> 5) * 64;
    } else if (t < 16384) {                // exp_wp
      int z = (t - 8192) >> 9, r = (t - 8192) & 511;
      in = expWp + (size_t)z * 2048 * 1024; out = oWp17 + (size_t)z * 2048 * 1024;
      K = 2048; N = 1024; n0 = (r & 15) * 64; k0 = (r >> 4) * 64;
    } else if (t < 16896) {                // sh_wf -> slot 16
      int r = t - 16384;
      in = shWf; out = oWf17 + (size_t)16 * 2048 * 1024;
      K = 1024; N = 2048; n0 = (r & 31) * 64; k0 = (r >> 5) * 64;
    } else if (t < 17408) {                // sh_wp -> slot 16
      int r = t - 16896;
      in = shWp; out = oWp17 + (size_t)16 * 2048 * 1024;
      K = 2048; N = 1024; n0 = (r & 15) * 64; k0 = (r >> 4) * 64;
    } else {                               // w_proj
      int r = t - 17408;
      in = wProj; out = oProj; K = 1024; N = 1024; n0 = (r & 15) * 64; k0 = (r >> 4) * 64;
    }
    tp_body(in, out, K, N, k0, n0, &sm.t[half][0], t256);
    return;
  }

  // ---- attention branch (R7-exact) ----
  int bh = u >> 4;
  int b = bh >> 4, h = bh & 15;
  int qb = 15 - (u & 15);                  // LPT
  int tid = threadIdx.x;
  int wv = tid >> 6, lane = tid & 63;
  int qrow0 = qb * 128 + wv * 16;
  const u16* qbase = qr + (size_t)bh * TSEQ * 64;
  const u16* kbase = kr + (size_t)bh * TSEQ * 64;
  const u16* vbase = vt + (size_t)bh * 64 * TSEQ;

  u16* pw = &sm.a.plds[wv][0];

  int r16 = lane & 15, g = lane >> 4;

  short8 aq0 = *(const short8*)(qbase + (size_t)(qrow0 + r16) * 64 + g * 8);
  short8 aq1 = *(const short8*)(qbase + (size_t)(qrow0 + r16) * 64 + 32 + g * 8);

  int sRow = tid >> 3;
  int sColE = (((tid & 7) * 16) ^ ((sRow & 7) << 4)) >> 1;

  float m[4] = {-1e30f, -1e30f, -1e30f, -1e30f};
  float l[4] = {0.f, 0.f, 0.f, 0.f};
  f32x4 o[4] = {};

  int nt = 2 * qb + 2;

  auto stage = [&](int t, int buf){
    int kp = t * 64;
    gload_lds16(kbase + ((size_t)(kp + sRow) << 6) + sColE,
                (char*)&sm.a.lK[buf][0] + wv * 1024);
    gload_lds16(vbase + (size_t)sRow * TSEQ + kp + sColE,
                (char*)&sm.a.lV[buf][0] + wv * 1024);
  };

  auto compute = [&](int t, int buf){
    int kp = t * 64;
    f32x4 s[4];
    __builtin_amdgcn_s_setprio(1);
#pragma unroll
    for (int st = 0; st < 4; ++st) {
      int rowK = st * 16 + r16;
      int sw = (rowK & 7) << 4;
      short8 kb0 = *(const short8*)((const char*)&sm.a.lK[buf][0] + rowK * 128 + ((g * 16) ^ sw));
      short8 kb1 = *(const short8*)((const char*)&sm.a.lK[buf][0] + rowK * 128 + ((64 + g * 16) ^ sw));
      f32x4 acc = {0.f, 0.f, 0.f, 0.f};
      acc = mfma16(aq0, kb0, acc);
      acc = mfma16(aq1, kb1, acc);
      s[st] = acc;
    }
    __builtin_amdgcn_s_setprio(0);

    float sc[4];
#pragma unroll
    for (int r = 0; r < 4; ++r) {
      int qpos = qrow0 + g * 4 + r;
      float v0 = (kp + r16      <= qpos) ? s[0][r] * 0.125f : -1e30f;
      float v1 = (kp + 16 + r16 <= qpos) ? s[1][r] * 0.125f : -1e30f;
      float v2 = (kp + 32 + r16 <= qpos) ? s[2][r] * 0.125f : -1e30f;
      float v3 = (kp + 48 + r16 <= qpos) ? s[3][r] * 0.125f : -1e30f;
      float mx = fmaxf(fmaxf(v0, v1), fmaxf(v2, v3));
      for (int d = 1; d < 16; d <<= 1) mx = fmaxf(mx, __shfl_xor(mx, d));
      float mnew = fmaxf(m[r], mx);
      float e0 = __expf(v0 - mnew), e1 = __expf(v1 - mnew);
      float e2 = __expf(v2 - mnew), e3 = __expf(v3 - mnew);
      float scale = __expf(m[r] - mnew);
      float rs = (e0 + e1) + (e2 + e3);
      for (int d = 1; d < 16; d <<= 1) rs += __shfl_xor(rs, d);
      l[r] = l[r] * scale + rs;
      m[r] = mnew;
      sc[r] = scale;
      int prow = (g * 4 + r) * 72;
      pw[prow + r16]      = f2bf(e0);
      pw[prow + 16 + r16] = f2bf(e1);
      pw[prow + 32 + r16] = f2bf(e2);
      pw[prow + 48 + r16] = f2bf(e3);
    }
#pragma unroll
    for (int c = 0; c < 4; ++c) {
      f32x4 t4 = o[c];
      t4[0] *= sc[0]; t4[1] *= sc[1]; t4[2] *= sc[2]; t4[3] *= sc[3];
      o[c] = t4;
    }

    short8 pa0 = *(const short8*)&pw[r16 * 72 + g * 8];
    short8 pa1 = *(const short8*)&pw[r16 * 72 + 32 + g * 8];
    __builtin_amdgcn_s_setprio(1);
#pragma unroll
    for (int c = 0; c < 4; ++c) {
      int rowV = c * 16 + r16;
      int sw = (rowV & 7) << 4;
      short8 vb0 = *(const short8*)((const char*)&sm.a.lV[buf][0] + rowV * 128 + ((g * 16) ^ sw));
      short8 vb1 = *(const short8*)((const char*)&sm.a.lV[buf][0] + rowV * 128 + ((64 + g * 16) ^ sw));
      o[c] = mfma16(pa0, vb0, o[c]);
      o[c] = mfma16(pa1, vb1, o[c]);
    }
    __builtin_amdgcn_s_setprio(0);
  };

  stage(0, 0);
  for (int t = 0; t < nt; ++t) {
    int buf = t & 1;
    if (t + 1 < nt) {
      stage(t + 1, buf ^ 1);
      asm volatile("s_waitcnt vmcnt(2)" ::: "memory");
    } else {
      asm volatile("s_waitcnt vmcnt(0)" ::: "memory");
    }
    __builtin_amdgcn_s_barrier();
    compute(t, buf);
    __builtin_amdgcn_s_barrier();
  }

#pragma unroll
  for (int c = 0; c < 4; ++c)
#pragma unroll
    for (int r = 0; r < 4; ++r) {
      int qpos = qrow0 + g * 4 + r;
      float val = o[c][r] / l[r];
      y[((size_t)(b * TSEQ + qpos)) * CDIM + h * 64 + c * 16 + r16] = f2bf(val);
    }
}

// ---------------- MoE routing ----------------
__global__ void zero_k(int* counts){
  int t = threadIdx.x;
  if (t < NEXP) counts[t] = 0;
}

__global__ void gate_k(const float* __restrict__ h2, const float* __restrict__ gw,
                       const float* __restrict__ gb,
                       int* __restrict__ route_e, float* __restrict__ route_w,
                       int* __restrict__ counts, float* __restrict__ probs)
{
  int n = blockIdx.x, tid = threadIdx.x;
  __shared__ float hrow[CDIM];
  __shared__ float part[16][17];
  __shared__ float sm[16];
  ((float4*)hrow)[tid] = ((const float4*)(h2 + (size_t)n * CDIM))[tid];
  __syncthreads();
  int e = tid & 15, seg = tid >> 4;
  const float4* gw4 = (const float4*)(gw + (size_t)e * CDIM + seg * 64);
  const float4* hs4 = (const float4*)(hrow + seg * 64);
  float p = 0.f;
#pragma unroll
  for (int i = 0; i < 16; ++i) {
    float4 gv = gw4[i];
    float4 hv = hs4[i];
    p += hv.x * gv.x;
    p += hv.y * gv.y;
    p += hv.z * gv.z;
    p += hv.w * gv.w;
  }
  part[e][seg] = p;
  __syncthreads();
  if (tid < 16) {
    float lg = 0.f;
    for (int s = 0; s < 16; ++s) lg += part[tid][s];
    sm[tid] = lg;
  }
  __syncthreads();
  if (tid == 0) {
    float mx = sm[0];
    for (int i = 1; i < 16; ++i) mx = fmaxf(mx, sm[i]);
    float ssum = 0.f;
    for (int i = 0; i < 16; ++i) { float pe = expf(sm[i] - mx); sm[i] = pe; ssum += pe; }
    float inv = 1.0f / ssum;
    for (int i = 0; i < 16; ++i) sm[i] *= inv;
    int i1 = -1; float b1 = -1e30f;
    for (int i = 0; i < 16; ++i) { float t = sm[i] + gb[i]; if (t > b1) { b1 = t; i1 = i; } }
    int i2 = -1; float b2 = -1e30f;
    for (int i = 0; i < 16; ++i) { if (i == i1) continue; float t = sm[i] + gb[i]; if (t > b2) { b2 = t; i2 = i; } }
    route_e[2 * n] = i1; route_e[2 * n + 1] = i2;
    route_w[2 * n] = sm[i1]; route_w[2 * n + 1] = sm[i2];
    atomicAdd(&counts[i1], 1); atomicAdd(&counts[i2], 1);
  }
  __syncthreads();
  if (tid < 16) probs[(size_t)n * 16 + tid] = sm[tid];
}

__global__ void scan_k(const int* counts, int* offs, int* cursors){
  if (threadIdx.x == 0) {
    int acc = 0;
    for (int e = 0; e < NEXP; ++e) { offs[e] = acc; cursors[e] = acc; acc += counts[e]; }
    offs[NEXP] = acc;
  }
}

__global__ void fill_k(const int* __restrict__ route_e, const float* __restrict__ route_w,
                       int* __restrict__ cursors, int* __restrict__ tok, float* __restrict__ tw,
                       int* __restrict__ inv)
{
  int n = blockIdx.x * 256 + threadIdx.x;
  if (n >= NTOK) return;
  for (int j = 0; j < 2; ++j) {
    int e = route_e[2 * n + j];
    int pos = atomicAdd(&cursors[e], 1);
    tok[pos] = n; tw[pos] = route_w[2 * n + j];
    inv[2 * n + j] = pos;
  }
}

// out[n] += eout[p0]*w0 + eout[p1]*w1   (eout bf16, downstream of routing)
__global__ void combine_k(float* __restrict__ out, const u16* __restrict__ eout,
                          const int* __restrict__ inv, const float* __restrict__ tw)
{
  int n = blockIdx.x, tid = threadIdx.x;
  int p0 = inv[2 * n], p1 = inv[2 * n + 1];
  float w0 = tw[p0], w1 = tw[p1];
  float4 a  = ((float4*)(out + (size_t)n * CDIM))[tid];
  ushort4 e0 = ((const ushort4*)(eout + (size_t)p0 * CDIM))[tid];
  ushort4 e1 = ((const ushort4*)(eout + (size_t)p1 * CDIM))[tid];
  a.x += bf2f(e0.x) * w0 + bf2f(e1.x) * w1;
  a.y += bf2f(e0.y) * w0 + bf2f(e1.y) * w1;
  a.z += bf2f(e0.z) * w0 + bf2f(e1.z) * w1;
  a.w += bf2f(e0.w) * w0 + bf2f(e1.w) * w1;
  ((float4*)(out + (size_t)n * CDIM))[tid] = a;
}

// deterministic psum reduction + lb loss
__global__ void lb2_k(const int* __restrict__ counts, const float* __restrict__ probs,
                      float* __restrict__ out)
{
  __shared__ float part[256][16];
  int t = threadIdx.x;
  float acc[16];
#pragma unroll
  for (int e = 0; e < 16; ++e) acc[e] = 0.f;
  for (int n = t; n < NTOK; n += 256) {
    const float4* row = (const float4*)(probs + (size_t)n * 16);
    float4 a0 = row[0], a1 = row[1], a2 = row[2], a3 = row[3];
    acc[0] += a0.x; acc[1] += a0.y; acc[2]  += a0.z; acc[3]  += a0.w;
    acc[4] += a1.x; acc[5] += a1.y; acc[6]  += a1.z; acc[7]  += a1.w;
    acc[8] += a2.x; acc[9] += a2.y; acc[10] += a2.z; acc[11] += a2.w;
    acc[12] += a3.x; acc[13] += a3.y; acc[14] += a3.z; acc[15] += a3.w;
  }
#pragma unroll
  for (int e = 0; e < 16; ++e) part[t][e] = acc[e];
  __syncthreads();
  __shared__ float colsum[16];
  if (t < 16) {
    float s = 0.f;
    for (int i = 0; i < 256; ++i) s += part[i][t];
    colsum[t] = s;
  }
  __syncthreads();
  if (t == 0) {
    float accl = 0.f;
    for (int e = 0; e < NEXP; ++e) {
      float f = (float)counts[e] * (16.0f / (2.0f * (float)NTOK + 1e-6f));
      accl += f * (colsum[e] * (1.0f / (float)NTOK));
    }
    out[0] = 0.01f * accl;
  }
}

// ---------------- launch ----------------
extern "C" void kernel_launch(void* const* d_in, const int* in_sizes, int n_in,
                              void* d_out, int out_size, void* d_ws, size_t ws_size,
                              hipStream_t stream)
{
  const float* x      = (const float*)d_in[0];
  const float* ln1_w  = (const float*)d_in[1];
  const float* ln2_w  = (const float*)d_in[2];
  const float* w_attn = (const float*)d_in[3];
  const float* b_attn = (const float*)d_in[4];
  const float* w_proj = (const float*)d_in[5];
  const float* b_proj = (const float*)d_in[6];
  const float* gate_w = (const float*)d_in[7];
  const float* gate_b = (const float*)d_in[8];
  const float* exp_wf = (const float*)d_in[9];
  const float* exp_bf = (const float*)d_in[10];
  const float* exp_wp = (const float*)d_in[11];
  const float* exp_bp = (const float*)d_in[12];
  const float* sh_wf  = (const float*)d_in[13];
  const float* sh_bf  = (const float*)d_in[14];
  const float* sh_wp  = (const float*)d_in[15];
  const float* sh_bp  = (const float*)d_in[16];

  char* ws = (char*)d_ws;
  size_t off = 0;
  auto alloc = [&](size_t b){ size_t r = off; off = (off + b + 255) & ~(size_t)255; return r; };

  size_t oWAttnT = alloc(3072ull * 1024 * 2);
  size_t oWProjT = alloc(1024ull * 1024 * 2);
  size_t oExpWfT = alloc(17ull * 2048 * 1024 * 2);   // slot 16 = sh_wf
  size_t oExpWpT = alloc(17ull * 1024 * 2048 * 2);   // slot 16 = sh_wp
  size_t oX2     = alloc(4096ull * 1024 * 4);
  size_t oH2F    = alloc(4096ull * 2048 * 2);   // h2 f32 16MB; later hid_sh bf16 [4096][2048]
  size_t oH2B    = alloc(4096ull * 1024 * 2);
  size_t oQKV    = alloc(4096ull * 3072 * 4);   // qkv f32 48MB; later hid_moe bf16 [8192][2048]=32MB
  size_t oQR     = alloc(4096ull * 1024 * 2);   // QR+KR+VT+H1B span; later eout bf16 [8192][1024]=16MB
  size_t oKR     = alloc(4096ull * 1024 * 2);
  size_t oVT     = alloc(4096ull * 1024 * 2);
  size_t oH1B    = alloc(4096ull * 1024 * 2);
  size_t oCnt    = alloc(128);
  size_t oOffs   = alloc(128);
  size_t oCurs   = alloc(128);
  size_t oRE     = alloc(8192ull * 4);
  size_t oRW     = alloc(8192ull * 4);
  size_t oTok    = alloc(8192ull * 4);
  size_t oTw     = alloc(8192ull * 4);
  size_t oInv    = alloc(8192ull * 4);
  size_t oProbs  = alloc(4096ull * 16 * 4);

  u16* pWAttnT = (u16*)(ws + oWAttnT);
  u16* pWProjT = (u16*)(ws + oWProjT);
  u16* pWf17   = (u16*)(ws + oExpWfT);
  u16* pWp17   = (u16*)(ws + oExpWpT);
  float* pX2   = (float*)(ws + oX2);
  float* pH2F  = (float*)(ws + oH2F);
  u16* pHidSh  = (u16*)(ws + oH2F);             // alias (h2f dead after gate_k)
  u16* pH2B    = (u16*)(ws + oH2B);
  float* pQKV  = (float*)(ws + oQKV);
  u16* pHidMoe = (u16*)(ws + oQKV);             // alias (qkv dead after rope), 32MB
  u16* pQR     = (u16*)(ws + oQR);
  u16* pKR     = (u16*)(ws + oKR);
  u16* pVT     = (u16*)(ws + oVT);
  u16* pH1B    = (u16*)(ws + oH1B);
  u16* pY      = (u16*)(ws + oH1B);             // alias (h1 dead after qkv gemm)
  u16* pEoutB  = (u16*)(ws + oQR);              // alias (qr/kr/vt dead), eout bf16 16MB
  int* pCnt    = (int*)(ws + oCnt);
  int* pOffs   = (int*)(ws + oOffs);
  int* pCurs   = (int*)(ws + oCurs);
  int* pRE     = (int*)(ws + oRE);
  float* pRW   = (float*)(ws + oRW);
  int* pTok    = (int*)(ws + oTok);
  float* pTw   = (float*)(ws + oTw);
  int* pInv    = (int*)(ws + oInv);
  float* pProbs= (float*)(ws + oProbs);

  // 1) early transpose: w_attn only
  transpose_wattn_k<<<768, 256, 0, stream>>>(w_attn, pWAttnT);

  // 2) rmsnorm1 -> h1 bf16
  rmsnorm_k<<<NTOK, 256, 0, stream>>>(x, ln1_w, pH1B, nullptr);

  // 3) qkv = h1 @ w_attn + b_attn  (f32)
  gemm_bt<0><<<dim3(3072/128, NTOK/128, 1), 256, 0, stream>>>(
      pH1B, 1024, pWAttnT, 0, b_attn, 0, pQKV, nullptr,
      NTOK, 3072, 1024, nullptr, nullptr, nullptr);

  // 4) rope + split
  rope_split_k<<<(NTOK * 16 * 32) / 256, 256, 0, stream>>>(pQKV, pQR, pKR, pVT);

  // 5) FUSED: causal flash attention + remaining weight transposes
  attn_tp_k<<<512 + 8832, 512, 0, stream>>>(pQR, pKR, pVT, pY,
                                            w_proj, sh_wf, sh_wp, exp_wf, exp_wp,
                                            pWProjT, pWf17, pWp17);

  // 6) x2 = x + y @ w_proj + b_proj
  gemm_bt<1><<<dim3(1024/128, NTOK/128, 1), 256, 0, stream>>>(
      pY, 1024, pWProjT, 0, b_proj, 0, pX2, x,
      NTOK, 1024, 1024, nullptr, nullptr, nullptr);

  // 7) rmsnorm2 -> h2 bf16 + f32
  rmsnorm_k<<<NTOK, 256, 0, stream>>>(pX2, ln2_w, pH2B, pH2F);

  // 8) routing
  zero_k<<<1, 64, 0, stream>>>(pCnt);
  gate_k<<<NTOK, 256, 0, stream>>>(pH2F, gate_w, gate_b, pRE, pRW, pCnt, pProbs);
  scan_k<<<1, 64, 0, stream>>>(pCnt, pOffs, pCurs);
  fill_k<<<NTOK/256, 256, 0, stream>>>(pRE, pRW, pCurs, pTok, pTw, pInv);
  lb2_k<<<1, 256, 0, stream>>>(pCnt, pProbs, ((float*)d_out) + (size_t)NTOK * CDIM);

  // 9) shared MLP: hid_sh = silu(h2 @ sh_wf + sh_bf)   (slot 16 of wf17)
  gemm_bt<2><<<dim3(2048/128, NTOK/128, 1), 256, 0, stream>>>(
      pH2B, 1024, pWf17 + (size_t)16 * 2048 * 1024, 0, sh_bf, 0, pHidSh, nullptr,
      NTOK, 2048, 1024, nullptr, nullptr, nullptr);

  // 10) d_out = x2 + hid_sh @ sh_wp + sh_bp   (slot 16 of wp17)
  gemm_bt<1><<<dim3(1024/128, NTOK/128, 1), 256, 0, stream>>>(
      pHidSh, 2048, pWp17 + (size_t)16 * 2048 * 1024, 0, sh_bp, 0, (float*)d_out, pX2,
      NTOK, 1024, 2048, nullptr, nullptr, nullptr);

  // 11) experts ff: hid_moe = silu(h2b[tok] @ wf_e + bf_e)
  gemm_bt<2><<<dim3(2048/128, NTOK/128, 16), 256, 0, stream>>>(
      pH2B, 1024, pWf17, 2048ll * 1024, exp_bf, 2048, pHidMoe, nullptr,
      NTOK, 2048, 1024, pCnt, pOffs, pTok);

  // 12) experts proj -> eout bf16 (downstream of routing; saves 32MB traffic)
  gemm_bt<4><<<dim3(1024/128, NTOK/128, 16), 256, 0, stream>>>(
      pHidMoe, 2048, pWp17, 2048ll * 1024, exp_bp, 1024, pEoutB, nullptr,
      NTOK, 1024, 2048, pCnt, pOffs, nullptr);

  // 13) d_out += eout[pos0]*w0 + eout[pos1]*w1
  combine_k<<<NTOK, 256, 0, stream>>>((float*)d_out, pEoutB, pInv, pTw);

  (void)in_sizes; (void)n_in; (void)out_size; (void)ws_size;
}

// Round 17
// 636.718 us; speedup vs baseline: 1.0800x; 1.0558x over previous
//
#include <hip/hip_runtime.h>

// ---------------- types & helpers ----------------
typedef __bf16 bf16x8 __attribute__((ext_vector_type(8)));
typedef short  short8 __attribute__((ext_vector_type(8)));
typedef float  f32x4  __attribute__((ext_vector_type(4)));
typedef unsigned short u16;

#define NTOK 4096   // B*T
#define TSEQ 2048
#define CDIM 1024
#define NEXP 16

__device__ __forceinline__ u16 f2bf(float f){
  union { float f; unsigned u; } v; v.f = f;
  unsigned r = v.u + 0x7fffu + ((v.u >> 16) & 1u);
  return (u16)(r >> 16);
}
__device__ __forceinline__ float bf2f(u16 u){
  union { unsigned u; float f; } v; v.u = ((unsigned)u) << 16; return v.f;
}

__device__ __forceinline__ f32x4 mfma16(short8 a, short8 b, f32x4 c){
  return __builtin_amdgcn_mfma_f32_16x16x32_bf16(
      __builtin_bit_cast(bf16x8, a), __builtin_bit_cast(bf16x8, b), c, 0, 0, 0);
}

__device__ __forceinline__ void gload_lds16(const void* g, void* l){
  __builtin_amdgcn_global_load_lds((__attribute__((address_space(1))) void*)g,
                                   (__attribute__((address_space(3))) void*)l,
                                   16, 0, 0);
}

// ---------------- transpose tile body (bit-identical output) ----------------
__device__ __forceinline__ void tp_body(const float* __restrict__ in, u16* __restrict__ out,
                                        int K, int N, int k0, int n0, u16* lds16, int tid)
{
  int tx = tid & 15;
#pragma unroll
  for (int p = 0; p < 2; ++p) {
    int q = (tid >> 4) + p * 16;
    int k = 2 * q;
    float4 v0 = *(const float4*)(in + (size_t)(k0 + k)     * N + n0 + tx * 4);
    float4 v1 = *(const float4*)(in + (size_t)(k0 + k + 1) * N + n0 + tx * 4);
    const float* a0 = (const float*)&v0;
    const float* a1 = (const float*)&v1;
#pragma unroll
    for (int i = 0; i < 4; ++i) {
      unsigned val = (unsigned)f2bf(a0[i]) | ((unsigned)f2bf(a1[i]) << 16);
      *(unsigned*)&lds16[(tx * 4 + i) * 66 + k] = val;
    }
  }
  __syncthreads();
#pragma unroll
  for (int p = 0; p < 2; ++p) {
    int n = (tid >> 3) + p * 32;
    int k8 = (tid & 7) * 8;
    const unsigned* l32 = (const unsigned*)&lds16[n * 66 + k8];
    uint4 o4;
    o4.x = l32[0]; o4.y = l32[1]; o4.z = l32[2]; o4.w = l32[3];
    *(uint4*)(out + (size_t)(n0 + n) * K + k0 + k8) = o4;
  }
}

// ---------------- early transpose: w_attn only ----------------
__global__ void transpose_wattn_k(const float* __restrict__ in, u16* __restrict__ out)
{
  __shared__ u16 lds16[64 * 66];
  int r = blockIdx.x;                     // 768 tiles: 48 n x 16 k
  int n0 = (r % 48) * 64, k0 = (r / 48) * 64;
  tp_body(in, out, 1024, 3072, k0, n0, lds16, threadIdx.x);
}

// ---------------- bias concat: [17][2048] and [17][1024] ----------------
__global__ void concat_bias_k(const float* __restrict__ exp_bf, const float* __restrict__ sh_bf,
                              const float* __restrict__ exp_bp, const float* __restrict__ sh_bp,
                              float* __restrict__ bf17, float* __restrict__ bp17)
{
  int i = blockIdx.x * 256 + threadIdx.x;
  if (i < 16 * 2048) bf17[i] = exp_bf[i];
  else if (i < 17 * 2048) bf17[i] = sh_bf[i - 16 * 2048];
  if (i < 16 * 1024) bp17[i] = exp_bp[i];
  else if (i < 17 * 1024) bp17[i] = sh_bp[i - 16 * 1024];
}

// ---------------- RMSNorm ----------------
__global__ void rmsnorm_k(const float* __restrict__ x, const float* __restrict__ w,
                          u16* __restrict__ ob, float* __restrict__ of)
{
  int row = blockIdx.x, tid = threadIdx.x;
  const float4* xr = (const float4*)(x + (size_t)row * CDIM);
  float4 v = xr[tid];
  float ss = v.x*v.x + v.y*v.y + v.z*v.z + v.w*v.w;
  for (int d = 1; d < 64; d <<= 1) ss += __shfl_xor(ss, d);
  __shared__ float wacc[4];
  if ((tid & 63) == 0) wacc[tid >> 6] = ss;
  __syncthreads();
  float tot = wacc[0] + wacc[1] + wacc[2] + wacc[3];
  float scale = rsqrtf(tot * (1.0f / CDIM) + 1e-5f);
  float4 wv = ((const float4*)w)[tid];
  float o0 = v.x * scale * wv.x, o1 = v.y * scale * wv.y;
  float o2 = v.z * scale * wv.z, o3 = v.w * scale * wv.w;
  if (of) ((float4*)(of + (size_t)row * CDIM))[tid] = make_float4(o0, o1, o2, o3);
  ushort4 ov; ov.x = f2bf(o0); ov.y = f2bf(o1); ov.z = f2bf(o2); ov.w = f2bf(o3);
  ((ushort4*)(ob + (size_t)row * CDIM))[tid] = ov;
}

// ---------------- GEMM: C[M,N] = A[M,K](bf16) @ Bt[N,K](bf16)^T + bias ----------------
// dbuf LDS + counted vmcnt. SWZ=1: XCD-chunked relabel (uniform density only);
// SWZ=0: plain blockIdx (for merged dense+ragged z-grids — R10 lesson).
// MODE 0: f32 ; 1: f32+resid ; 2: bf16 silu ; 4: bf16 plain ;
// 5: qkv fused-v (cols<2048 f32 to Cout[N=3072]; cols>=2048 bf16 direct to vt layout)
template<int MODE, int SWZ>
__global__ void __launch_bounds__(256, 4)
gemm_bt(const u16* __restrict__ A, int lda,
        const u16* __restrict__ Bt, long long bStrideZ,
        const float* __restrict__ bias, int biasStrideZ,
        void* __restrict__ Cout,
        const float* __restrict__ resid,
        int M, int N, int K,
        const int* __restrict__ counts, const int* __restrict__ offsets,
        const int* __restrict__ tokA, u16* __restrict__ vtp)
{
  int cb, rb, z;
  if (SWZ) {
    int nwg = gridDim.x * gridDim.y * gridDim.z;
    int d = (blockIdx.z * gridDim.y + blockIdx.y) * gridDim.x + blockIdx.x;
    int o = (d & 7) * (nwg >> 3) + (d >> 3);
    cb = o % gridDim.x;
    int t2 = o / gridDim.x;
    rb = t2 % gridDim.y;
    z  = t2 / gridDim.y;
  } else {
    cb = blockIdx.x; rb = blockIdx.y; z = blockIdx.z;
  }

  int mLoc = M, rowBase = 0;
  if (counts) { mLoc = counts[z]; rowBase = offsets[z]; }
  if (rb * 128 >= mLoc) return;

  const u16* Bz = Bt + (size_t)z * bStrideZ;
  const float* bz = bias + (size_t)z * biasStrideZ;

  __shared__ u16 lds_a[2][128 * 32];
  __shared__ u16 lds_b[2][128 * 32];

  int tid = threadIdx.x;
  int lane = tid & 63, wave = tid >> 6;
  int wm = wave >> 1, wn = wave & 1;
  int srow = wave * 16 + (lane >> 2);
  int skel = (lane & 3) * 8;
  int r16 = lane & 15, g8 = (lane >> 4) * 8;

  size_t arow[2];
  int ncol[2];
#pragma unroll
  for (int c = 0; c < 2; ++c) {
    int rloc = rb * 128 + c * 64 + srow;
    if (rloc >= mLoc) rloc = mLoc - 1;
    int grow = rowBase + rloc;
    arow[c] = tokA ? (size_t)tokA[grow] : (size_t)grow;
    ncol[c] = cb * 128 + c * 64 + srow;
  }

  f32x4 acc[4][4] = {};

  auto stage = [&](int kt, int buf){
    int k0 = kt * 32;
#pragma unroll
    for (int c = 0; c < 2; ++c) {
      gload_lds16(A + arow[c] * lda + k0 + skel,
                  (char*)&lds_a[buf][0] + c * 4096 + wave * 1024);
      gload_lds16(Bz + (size_t)ncol[c] * K + k0 + skel,
                  (char*)&lds_b[buf][0] + c * 4096 + wave * 1024);
    }
  };

  int nkt = K >> 5;
  stage(0, 0);
  for (int kt = 0; kt < nkt; ++kt) {
    int buf = kt & 1;
    if (kt + 1 < nkt) {
      stage(kt + 1, buf ^ 1);
      asm volatile("s_waitcnt vmcnt(4)" ::: "memory");
    } else {
      asm volatile("s_waitcnt vmcnt(0)" ::: "memory");
    }
    __builtin_amdgcn_s_barrier();
    short8 af[4], bfr[4];
#pragma unroll
    for (int i = 0; i < 4; ++i) {
      af[i]  = *(const short8*)&lds_a[buf][(wm * 64 + i * 16 + r16) * 32 + g8];
      bfr[i] = *(const short8*)&lds_b[buf][(wn * 64 + i * 16 + r16) * 32 + g8];
    }
#pragma unroll
    for (int i = 0; i < 4; ++i)
#pragma unroll
      for (int j = 0; j < 4; ++j)
        acc[i][j] = mfma16(af[i], bfr[j], acc[i][j]);
    __builtin_amdgcn_s_barrier();
  }

  // epilogue: row = (lane>>4)*4 + r, col = lane&15
#pragma unroll
  for (int i = 0; i < 4; ++i) {
    int rl0 = rb * 128 + wm * 64 + i * 16 + (lane >> 4) * 4;
#pragma unroll
    for (int j = 0; j < 4; ++j) {
      int col = cb * 128 + wn * 64 + j * 16 + r16;
      float bv = bz[col];
#pragma unroll
      for (int r = 0; r < 4; ++r) {
        int rl = rl0 + r;
        if (rl >= mLoc) continue;
        int grow = rowBase + rl;
        float v = acc[i][j][r] + bv;
        if (MODE == 0) {
          ((float*)Cout)[(size_t)grow * N + col] = v;
        } else if (MODE == 1) {
          ((float*)Cout)[(size_t)grow * N + col] = v + resid[(size_t)grow * N + col];
        } else if (MODE == 2) {
          float s = v * (1.0f / (1.0f + __expf(-v)));
          ((u16*)Cout)[(size_t)grow * N + col] = f2bf(s);
        } else if (MODE == 4) {
          ((u16*)Cout)[(size_t)grow * N + col] = f2bf(v);
        } else {
          // MODE 5: q/k cols -> f32 buffer (for rope); v cols -> bf16 direct to vt
          if (col < 2048) {
            ((float*)Cout)[(size_t)grow * N + col] = v;
          } else {
            int c10 = col - 2048;
            int h = c10 >> 6, dd = c10 & 63;
            int b = grow >> 11, t = grow & 2047;
            vtp[((size_t)(b * 16 + h) * 64 + dd) * TSEQ + t] = f2bf(v);
          }
        }
      }
    }
  }
}

// ---------------- RoPE (q,k only): qkv f32 -> q,k [BH][T][D] bf16 ----------------
__global__ void rope_qk_k(const float* __restrict__ qkv,
                          u16* __restrict__ qr, u16* __restrict__ kr)
{
  int flat = blockIdx.x * 256 + threadIdx.x;
  int i = flat & 31;
  int h = (flat >> 5) & 15;
  int n = flat >> 9;
  int b = n >> 11, t = n & 2047;
  const float* row = qkv + (size_t)n * 3072;
  float2 q = *(const float2*)(row + h * 64 + 2 * i);
  float2 k = *(const float2*)(row + 1024 + h * 64 + 2 * i);
  float freq = expf(-(float)i * (2.0f / 64.0f) * 9.210340371976184f);
  float ang = (float)t * freq;
  float sn, cs;
  sincosf(ang, &sn, &cs);
  float q0 = q.x * cs - q.y * sn, q1 = q.x * sn + q.y * cs;
  float k0 = k.x * cs - k.y * sn, k1 = k.x * sn + k.y * cs;
  int bh = b * 16 + h;
  size_t qoff = ((size_t)bh * TSEQ + t) * 64 + 2 * i;
  *(unsigned*)(qr + qoff) = (unsigned)f2bf(q0) | ((unsigned)f2bf(q1) << 16);
  *(unsigned*)(kr + qoff) = (unsigned)f2bf(k0) | ((unsigned)f2bf(k1) << 16);
}

// ---------------- FUSED: flash attention (512 blocks) + weight transposes (8832 blocks) ----------------
__global__ void __launch_bounds__(512, 4)
attn_tp_k(const u16* __restrict__ qr, const u16* __restrict__ kr,
          const u16* __restrict__ vt, u16* __restrict__ y,
          const float* __restrict__ wProj, const float* __restrict__ shWf,
          const float* __restrict__ shWp,  const float* __restrict__ expWf,
          const float* __restrict__ expWp,
          u16* __restrict__ oProj, u16* __restrict__ oWf17, u16* __restrict__ oWp17)
{
  __shared__ union {
    struct { u16 lK[2][64 * 64]; u16 lV[2][64 * 64]; u16 plds[8][16 * 72]; } a;  // 51200 B
    u16 t[2][64 * 66];                                                            // 16896 B
  } sm;

  int u = blockIdx.x;
  if (u >= 512) {
    int tid = threadIdx.x;
    int half = tid >> 8, t256 = tid & 255;
    int t = (u - 512) * 2 + half;          // 0..17663
    const float* in; u16* out; int K, N, k0, n0;
    if (t < 8192) {                        // exp_wf
      int z = t >> 9, r = t & 511;
      in = expWf + (size_t)z * 2048 * 1024; out = oWf17 + (size_t)z * 2048 * 1024;
      K = 1024; N = 2048; n0 = (r & 31) * 64; k0 = (r >> 5) * 64;
    } else if (t < 16384) {                // exp_wp
      int z = (t - 8192) >> 9, r = (t - 8192) & 511;
      in = expWp + (size_t)z * 2048 * 1024; out = oWp17 + (size_t)z * 2048 * 1024;
      K = 2048; N = 1024; n0 = (r & 15) * 64; k0 = (r >> 4) * 64;
    } else if (t < 16896) {                // sh_wf -> slot 16
      int r = t - 16384;
      in = shWf; out = oWf17 + (size_t)16 * 2048 * 1024;
      K = 1024; N = 2048; n0 = (r & 31) * 64; k0 = (r >> 5) * 64;
    } else if (t < 17408) {                // sh_wp -> slot 16
      int r = t - 16896;
      in = shWp; out = oWp17 + (size_t)16 * 2048 * 1024;
      K = 2048; N = 1024; n0 = (r & 15) * 64; k0 = (r >> 4) * 64;
    } else {                               // w_proj
      int r = t - 17408;
      in = wProj; out = oProj; K = 1024; N = 1024; n0 = (r & 15) * 64; k0 = (r >> 4) * 64;
    }
    tp_body(in, out, K, N, k0, n0, &sm.t[half][0], t256);
    return;
  }

  // ---- attention branch (R7-exact) ----
  int bh = u >> 4;
  int b = bh >> 4, h = bh & 15;
  int qb = 15 - (u & 15);                  // LPT
  int tid = threadIdx.x;
  int wv = tid >> 6, lane = tid & 63;
  int qrow0 = qb * 128 + wv * 16;
  const u16* qbase = qr + (size_t)bh * TSEQ * 64;
  const u16* kbase = kr + (size_t)bh * TSEQ * 64;
  const u16* vbase = vt + (size_t)bh * 64 * TSEQ;

  u16* pw = &sm.a.plds[wv][0];

  int r16 = lane & 15, g = lane >> 4;

  short8 aq0 = *(const short8*)(qbase + (size_t)(qrow0 + r16) * 64 + g * 8);
  short8 aq1 = *(const short8*)(qbase + (size_t)(qrow0 + r16) * 64 + 32 + g * 8);

  int sRow = tid >> 3;
  int sColE = (((tid & 7) * 16) ^ ((sRow & 7) << 4)) >> 1;

  float m[4] = {-1e30f, -1e30f, -1e30f, -1e30f};
  float l[4] = {0.f, 0.f, 0.f, 0.f};
  f32x4 o[4] = {};

  int nt = 2 * qb + 2;

  auto stage = [&](int t, int buf){
    int kp = t * 64;
    gload_lds16(kbase + ((size_t)(kp + sRow) << 6) + sColE,
                (char*)&sm.a.lK[buf][0] + wv * 1024);
    gload_lds16(vbase + (size_t)sRow * TSEQ + kp + sColE,
                (char*)&sm.a.lV[buf][0] + wv * 1024);
  };

  auto compute = [&](int t, int buf){
    int kp = t * 64;
    f32x4 s[4];
    __builtin_amdgcn_s_setprio(1);
#pragma unroll
    for (int st = 0; st < 4; ++st) {
      int rowK = st * 16 + r16;
      int sw = (rowK & 7) << 4;
      short8 kb0 = *(const short8*)((const char*)&sm.a.lK[buf][0] + rowK * 128 + ((g * 16) ^ sw));
      short8 kb1 = *(const short8*)((const char*)&sm.a.lK[buf][0] + rowK * 128 + ((64 + g * 16) ^ sw));
      f32x4 acc = {0.f, 0.f, 0.f, 0.f};
      acc = mfma16(aq0, kb0, acc);
      acc = mfma16(aq1, kb1, acc);
      s[st] = acc;
    }
    __builtin_amdgcn_s_setprio(0);

    float sc[4];
#pragma unroll
    for (int r = 0; r < 4; ++r) {
      int qpos = qrow0 + g * 4 + r;
      float v0 = (kp + r16      <= qpos) ? s[0][r] * 0.125f : -1e30f;
      float v1 = (kp + 16 + r16 <= qpos) ? s[1][r] * 0.125f : -1e30f;
      float v2 = (kp + 32 + r16 <= qpos) ? s[2][r] * 0.125f : -1e30f;
      float v3 = (kp + 48 + r16 <= qpos) ? s[3][r] * 0.125f : -1e30f;
      float mx = fmaxf(fmaxf(v0, v1), fmaxf(v2, v3));
      for (int d = 1; d < 16; d <<= 1) mx = fmaxf(mx, __shfl_xor(mx, d));
      float mnew = fmaxf(m[r], mx);
      float e0 = __expf(v0 - mnew), e1 = __expf(v1 - mnew);
      float e2 = __expf(v2 - mnew), e3 = __expf(v3 - mnew);
      float scale = __expf(m[r] - mnew);
      float rs = (e0 + e1) + (e2 + e3);
      for (int d = 1; d < 16; d <<= 1) rs += __shfl_xor(rs, d);
      l[r] = l[r] * scale + rs;
      m[r] = mnew;
      sc[r] = scale;
      int prow = (g * 4 + r) * 72;
      pw[prow + r16]      = f2bf(e0);
      pw[prow + 16 + r16] = f2bf(e1);
      pw[prow + 32 + r16] = f2bf(e2);
      pw[prow + 48 + r16] = f2bf(e3);
    }
#pragma unroll
    for (int c = 0; c < 4; ++c) {
      f32x4 t4 = o[c];
      t4[0] *= sc[0]; t4[1] *= sc[1]; t4[2] *= sc[2]; t4[3] *= sc[3];
      o[c] = t4;
    }

    short8 pa0 = *(const short8*)&pw[r16 * 72 + g * 8];
    short8 pa1 = *(const short8*)&pw[r16 * 72 + 32 + g * 8];
    __builtin_amdgcn_s_setprio(1);
#pragma unroll
    for (int c = 0; c < 4; ++c) {
      int rowV = c * 16 + r16;
      int sw = (rowV & 7) << 4;
      short8 vb0 = *(const short8*)((const char*)&sm.a.lV[buf][0] + rowV * 128 + ((g * 16) ^ sw));
      short8 vb1 = *(const short8*)((const char*)&sm.a.lV[buf][0] + rowV * 128 + ((64 + g * 16) ^ sw));
      o[c] = mfma16(pa0, vb0, o[c]);
      o[c] = mfma16(pa1, vb1, o[c]);
    }
    __builtin_amdgcn_s_setprio(0);
  };

  stage(0, 0);
  for (int t = 0; t < nt; ++t) {
    int buf = t & 1;
    if (t + 1 < nt) {
      stage(t + 1, buf ^ 1);
      asm volatile("s_waitcnt vmcnt(2)" ::: "memory");
    } else {
      asm volatile("s_waitcnt vmcnt(0)" ::: "memory");
    }
    __builtin_amdgcn_s_barrier();
    compute(t, buf);
    __builtin_amdgcn_s_barrier();
  }

#pragma unroll
  for (int c = 0; c < 4; ++c)
#pragma unroll
    for (int r = 0; r < 4; ++r) {
      int qpos = qrow0 + g * 4 + r;
      float val = o[c][r] / l[r];
      y[((size_t)(b * TSEQ + qpos)) * CDIM + h * 64 + c * 16 + r16] = f2bf(val);
    }
}

// ---------------- MoE routing ----------------
__global__ void zero_k(int* counts){
  int t = threadIdx.x;
  if (t < NEXP) counts[t] = 0;
  if (t == NEXP) counts[NEXP] = NTOK;   // shared pseudo-expert (dense)
}

__global__ void gate_k(const float* __restrict__ h2, const float* __restrict__ gw,
                       const float* __restrict__ gb,
                       int* __restrict__ route_e, float* __restrict__ route_w,
                       int* __restrict__ counts, float* __restrict__ probs)
{
  int n = blockIdx.x, tid = threadIdx.x;
  __shared__ float hrow[CDIM];
  __shared__ float part[16][17];
  __shared__ float sm[16];
  ((float4*)hrow)[tid] = ((const float4*)(h2 + (size_t)n * CDIM))[tid];
  __syncthreads();
  int e = tid & 15, seg = tid >> 4;
  const float4* gw4 = (const float4*)(gw + (size_t)e * CDIM + seg * 64);
  const float4* hs4 = (const float4*)(hrow + seg * 64);
  float p = 0.f;
#pragma unroll
  for (int i = 0; i < 16; ++i) {
    float4 gv = gw4[i];
    float4 hv = hs4[i];
    p += hv.x * gv.x;
    p += hv.y * gv.y;
    p += hv.z * gv.z;
    p += hv.w * gv.w;
  }
  part[e][seg] = p;
  __syncthreads();
  if (tid < 16) {
    float lg = 0.f;
    for (int s = 0; s < 16; ++s) lg += part[tid][s];
    sm[tid] = lg;
  }
  __syncthreads();
  if (tid == 0) {
    float mx = sm[0];
    for (int i = 1; i < 16; ++i) mx = fmaxf(mx, sm[i]);
    float ssum = 0.f;
    for (int i = 0; i < 16; ++i) { float pe = expf(sm[i] - mx); sm[i] = pe; ssum += pe; }
    float inv = 1.0f / ssum;
    for (int i = 0; i < 16; ++i) sm[i] *= inv;
    int i1 = -1; float b1 = -1e30f;
    for (int i = 0; i < 16; ++i) { float t = sm[i] + gb[i]; if (t > b1) { b1 = t; i1 = i; } }
    int i2 = -1; float b2 = -1e30f;
    for (int i = 0; i < 16; ++i) { if (i == i1) continue; float t = sm[i] + gb[i]; if (t > b2) { b2 = t; i2 = i; } }
    route_e[2 * n] = i1; route_e[2 * n + 1] = i2;
    route_w[2 * n] = sm[i1]; route_w[2 * n + 1] = sm[i2];
    atomicAdd(&counts[i1], 1); atomicAdd(&counts[i2], 1);
  }
  __syncthreads();
  if (tid < 16) probs[(size_t)n * 16 + tid] = sm[tid];
}

__global__ void scan_k(const int* counts, int* offs, int* cursors){
  if (threadIdx.x == 0) {
    int acc = 0;
    for (int e = 0; e < NEXP; ++e) { offs[e] = acc; cursors[e] = acc; acc += counts[e]; }
    offs[NEXP] = acc;   // = 8192, rowBase for shared pseudo-expert
  }
}

__global__ void fill_k(const int* __restrict__ route_e, const float* __restrict__ route_w,
                       int* __restrict__ cursors, int* __restrict__ tok, float* __restrict__ tw,
                       int* __restrict__ inv)
{
  int n = blockIdx.x * 256 + threadIdx.x;
  if (n >= NTOK) return;
  for (int j = 0; j < 2; ++j) {
    int e = route_e[2 * n + j];
    int pos = atomicAdd(&cursors[e], 1);
    tok[pos] = n; tw[pos] = route_w[2 * n + j];
    inv[2 * n + j] = pos;
  }
  tok[2 * NTOK + n] = n;   // shared pseudo-expert: identity gather
}

// out[n] = x2[n] + esh[n] + e0*w0 + e1*w1   (eout bf16, downstream of routing)
__global__ void combine_k(float* __restrict__ out, const float* __restrict__ x2,
                          const u16* __restrict__ eout,
                          const int* __restrict__ inv, const float* __restrict__ tw)
{
  int n = blockIdx.x, tid = threadIdx.x;
  int p0 = inv[2 * n], p1 = inv[2 * n + 1];
  float w0 = tw[p0], w1 = tw[p1];
  float4 xr = ((const float4*)(x2 + (size_t)n * CDIM))[tid];
  ushort4 es = ((const ushort4*)(eout + (size_t)(2 * NTOK + n) * CDIM))[tid];
  float4 a;
  a.x = xr.x + bf2f(es.x);
  a.y = xr.y + bf2f(es.y);
  a.z = xr.z + bf2f(es.z);
  a.w = xr.w + bf2f(es.w);
  ushort4 e0 = ((const ushort4*)(eout + (size_t)p0 * CDIM))[tid];
  ushort4 e1 = ((const ushort4*)(eout + (size_t)p1 * CDIM))[tid];
  a.x += bf2f(e0.x) * w0 + bf2f(e1.x) * w1;
  a.y += bf2f(e0.y) * w0 + bf2f(e1.y) * w1;
  a.z += bf2f(e0.z) * w0 + bf2f(e1.z) * w1;
  a.w += bf2f(e0.w) * w0 + bf2f(e1.w) * w1;
  ((float4*)(out + (size_t)n * CDIM))[tid] = a;
}

// deterministic psum reduction + lb loss
__global__ void lb2_k(const int* __restrict__ counts, const float* __restrict__ probs,
                      float* __restrict__ out)
{
  __shared__ float part[256][16];
  int t = threadIdx.x;
  float acc[16];
#pragma unroll
  for (int e = 0; e < 16; ++e) acc[e] = 0.f;
  for (int n = t; n < NTOK; n += 256) {
    const float4* row = (const float4*)(probs + (size_t)n * 16);
    float4 a0 = row[0], a1 = row[1], a2 = row[2], a3 = row[3];
    acc[0] += a0.x; acc[1] += a0.y; acc[2]  += a0.z; acc[3]  += a0.w;
    acc[4] += a1.x; acc[5] += a1.y; acc[6]  += a1.z; acc[7]  += a1.w;
    acc[8] += a2.x; acc[9] += a2.y; acc[10] += a2.z; acc[11] += a2.w;
    acc[12] += a3.x; acc[13] += a3.y; acc[14] += a3.z; acc[15] += a3.w;
  }
#pragma unroll
  for (int e = 0; e < 16; ++e) part[t][e] = acc[e];
  __syncthreads();
  __shared__ float colsum[16];
  if (t < 16) {
    float s = 0.f;
    for (int i = 0; i < 256; ++i) s += part[i][t];
    colsum[t] = s;
  }
  __syncthreads();
  if (t == 0) {
    float accl = 0.f;
    for (int e = 0; e < NEXP; ++e) {
      float f = (float)counts[e] * (16.0f / (2.0f * (float)NTOK + 1e-6f));
      accl += f * (colsum[e] * (1.0f / (float)NTOK));
    }
    out[0] = 0.01f * accl;
  }
}

// ---------------- launch ----------------
extern "C" void kernel_launch(void* const* d_in, const int* in_sizes, int n_in,
                              void* d_out, int out_size, void* d_ws, size_t ws_size,
                              hipStream_t stream)
{
  const float* x      = (const float*)d_in[0];
  const float* ln1_w  = (const float*)d_in[1];
  const float* ln2_w  = (const float*)d_in[2];
  const float* w_attn = (const float*)d_in[3];
  const float* b_attn = (const float*)d_in[4];
  const float* w_proj = (const float*)d_in[5];
  const float* b_proj = (const float*)d_in[6];
  const float* gate_w = (const float*)d_in[7];
  const float* gate_b = (const float*)d_in[8];
  const float* exp_wf = (const float*)d_in[9];
  const float* exp_bf = (const float*)d_in[10];
  const float* exp_wp = (const float*)d_in[11];
  const float* exp_bp = (const float*)d_in[12];
  const float* sh_wf  = (const float*)d_in[13];
  const float* sh_bf  = (const float*)d_in[14];
  const float* sh_wp  = (const float*)d_in[15];
  const float* sh_bp  = (const float*)d_in[16];

  char* ws = (char*)d_ws;
  size_t off = 0;
  auto alloc = [&](size_t b){ size_t r = off; off = (off + b + 255) & ~(size_t)255; return r; };

  size_t oWAttnT = alloc(3072ull * 1024 * 2);
  size_t oWProjT = alloc(1024ull * 1024 * 2);
  size_t oExpWfT = alloc(17ull * 2048 * 1024 * 2);   // slot 16 = sh_wf
  size_t oExpWpT = alloc(17ull * 1024 * 2048 * 2);   // slot 16 = sh_wp
  size_t oX2     = alloc(4096ull * 1024 * 4);
  size_t oH2F    = alloc(4096ull * 1024 * 4);        // h2 f32 16MB
  size_t oH2B    = alloc(4096ull * 1024 * 2);
  size_t oQKV    = alloc(4096ull * 3072 * 4);        // qkv f32 48MB; later hid17 bf16 [12288][2048]=48MB
  size_t oQR     = alloc(4096ull * 1024 * 2);        // QR+KR+VT = 24MB span; later eout bf16 [12288][1024]=24MB
  size_t oKR     = alloc(4096ull * 1024 * 2);
  size_t oVT     = alloc(4096ull * 1024 * 2);
  size_t oH1B    = alloc(4096ull * 1024 * 2);        // h1; later y
  size_t oCnt    = alloc(128);
  size_t oOffs   = alloc(128);
  size_t oCurs   = alloc(128);
  size_t oRE     = alloc(8192ull * 4);
  size_t oRW     = alloc(8192ull * 4);
  size_t oTok    = alloc(12288ull * 4);
  size_t oTw     = alloc(8192ull * 4);
  size_t oInv    = alloc(8192ull * 4);
  size_t oProbs  = alloc(4096ull * 16 * 4);
  size_t oBf17   = alloc(17ull * 2048 * 4);
  size_t oBp17   = alloc(17ull * 1024 * 4);

  u16* pWAttnT = (u16*)(ws + oWAttnT);
  u16* pWProjT = (u16*)(ws + oWProjT);
  u16* pWf17   = (u16*)(ws + oExpWfT);
  u16* pWp17   = (u16*)(ws + oExpWpT);
  float* pX2   = (float*)(ws + oX2);
  float* pH2F  = (float*)(ws + oH2F);
  u16* pH2B    = (u16*)(ws + oH2B);
  float* pQKV  = (float*)(ws + oQKV);
  u16* pHid17  = (u16*)(ws + oQKV);             // alias (qkv dead after rope/attn staging)
  u16* pQR     = (u16*)(ws + oQR);
  u16* pKR     = (u16*)(ws + oKR);
  u16* pVT     = (u16*)(ws + oVT);
  u16* pH1B    = (u16*)(ws + oH1B);
  u16* pY      = (u16*)(ws + oH1B);             // alias (h1 dead after qkv gemm)
  u16* pEoutB  = (u16*)(ws + oQR);              // alias (qr/kr/vt dead), eout bf16 24MB
  int* pCnt    = (int*)(ws + oCnt);
  int* pOffs   = (int*)(ws + oOffs);
  int* pCurs   = (int*)(ws + oCurs);
  int* pRE     = (int*)(ws + oRE);
  float* pRW   = (float*)(ws + oRW);
  int* pTok    = (int*)(ws + oTok);
  float* pTw   = (float*)(ws + oTw);
  int* pInv    = (int*)(ws + oInv);
  float* pProbs= (float*)(ws + oProbs);
  float* pBf17 = (float*)(ws + oBf17);
  float* pBp17 = (float*)(ws + oBp17);

  // 1) early transpose (w_attn) + bias concat
  transpose_wattn_k<<<768, 256, 0, stream>>>(w_attn, pWAttnT);
  concat_bias_k<<<(17 * 2048 + 255) / 256, 256, 0, stream>>>(exp_bf, sh_bf, exp_bp, sh_bp, pBf17, pBp17);

  // 2) rmsnorm1 -> h1 bf16
  rmsnorm_k<<<NTOK, 256, 0, stream>>>(x, ln1_w, pH1B, nullptr);

  // 3) qkv GEMM, MODE5: q/k cols f32 -> pQKV; v cols bf16 direct -> vt
  gemm_bt<5, 1><<<dim3(3072/128, NTOK/128, 1), 256, 0, stream>>>(
      pH1B, 1024, pWAttnT, 0, b_attn, 0, pQKV, nullptr,
      NTOK, 3072, 1024, nullptr, nullptr, nullptr, pVT);

  // 4) rope (q,k only)
  rope_qk_k<<<(NTOK * 16 * 32) / 256, 256, 0, stream>>>(pQKV, pQR, pKR);

  // 5) FUSED: causal flash attention + remaining weight transposes
  attn_tp_k<<<512 + 8832, 512, 0, stream>>>(pQR, pKR, pVT, pY,
                                            w_proj, sh_wf, sh_wp, exp_wf, exp_wp,
                                            pWProjT, pWf17, pWp17);

  // 6) x2 = x + y @ w_proj + b_proj
  gemm_bt<1, 1><<<dim3(1024/128, NTOK/128, 1), 256, 0, stream>>>(
      pY, 1024, pWProjT, 0, b_proj, 0, pX2, x,
      NTOK, 1024, 1024, nullptr, nullptr, nullptr, nullptr);

  // 7) rmsnorm2 -> h2 bf16 + f32
  rmsnorm_k<<<NTOK, 256, 0, stream>>>(pX2, ln2_w, pH2B, pH2F);

  // 8) routing
  zero_k<<<1, 64, 0, stream>>>(pCnt);
  gate_k<<<NTOK, 256, 0, stream>>>(pH2F, gate_w, gate_b, pRE, pRW, pCnt, pProbs);
  scan_k<<<1, 64, 0, stream>>>(pCnt, pOffs, pCurs);
  fill_k<<<NTOK/256, 256, 0, stream>>>(pRE, pRW, pCurs, pTok, pTw, pInv);
  lb2_k<<<1, 256, 0, stream>>>(pCnt, pProbs, ((float*)d_out) + (size_t)NTOK * CDIM);

  // 9) MERGED ff (experts z=0..15 ragged + shared z=16 dense), SWZ=0 (round-robin balance)
  gemm_bt<2, 0><<<dim3(2048/128, NTOK/128, 17), 256, 0, stream>>>(
      pH2B, 1024, pWf17, 2048ll * 1024, pBf17, 2048, pHid17, nullptr,
      NTOK, 2048, 1024, pCnt, pOffs, pTok, nullptr);

  // 10) MERGED proj -> eout bf16 [12288][1024], SWZ=0
  gemm_bt<4, 0><<<dim3(1024/128, NTOK/128, 17), 256, 0, stream>>>(
      pHid17, 2048, pWp17, 2048ll * 1024, pBp17, 1024, pEoutB, nullptr,
      NTOK, 1024, 2048, pCnt, pOffs, nullptr, nullptr);

  // 11) d_out = x2 + esh + e0*w0 + e1*w1
  combine_k<<<NTOK, 256, 0, stream>>>((float*)d_out, pX2, pEoutB, pInv, pTw);

  (void)in_sizes; (void)n_in; (void)out_size; (void)ws_size;
}

// Round 18
// 591.043 us; speedup vs baseline: 1.1634x; 1.0773x over previous
//
#include <hip/hip_runtime.h>

// ---------------- types & helpers ----------------
typedef __bf16 bf16x8 __attribute__((ext_vector_type(8)));
typedef short  short8 __attribute__((ext_vector_type(8)));
typedef float  f32x4  __attribute__((ext_vector_type(4)));
typedef unsigned short u16;

#define NTOK 4096   // B*T
#define TSEQ 2048
#define CDIM 1024
#define NEXP 16

__device__ __forceinline__ u16 f2bf(float f){
  union { float f; unsigned u; } v; v.f = f;
  unsigned r = v.u + 0x7fffu + ((v.u >> 16) & 1u);
  return (u16)(r >> 16);
}
__device__ __forceinline__ float bf2f(u16 u){
  union { unsigned u; float f; } v; v.u = ((unsigned)u) << 16; return v.f;
}

__device__ __forceinline__ f32x4 mfma16(short8 a, short8 b, f32x4 c){
  return __builtin_amdgcn_mfma_f32_16x16x32_bf16(
      __builtin_bit_cast(bf16x8, a), __builtin_bit_cast(bf16x8, b), c, 0, 0, 0);
}

__device__ __forceinline__ void gload_lds16(const void* g, void* l){
  __builtin_amdgcn_global_load_lds((__attribute__((address_space(1))) void*)g,
                                   (__attribute__((address_space(3))) void*)l,
                                   16, 0, 0);
}

// ---------------- transpose tile body (bit-identical output) ----------------
__device__ __forceinline__ void tp_body(const float* __restrict__ in, u16* __restrict__ out,
                                        int K, int N, int k0, int n0, u16* lds16, int tid)
{
  int tx = tid & 15;
#pragma unroll
  for (int p = 0; p < 2; ++p) {
    int q = (tid >> 4) + p * 16;
    int k = 2 * q;
    float4 v0 = *(const float4*)(in + (size_t)(k0 + k)     * N + n0 + tx * 4);
    float4 v1 = *(const float4*)(in + (size_t)(k0 + k + 1) * N + n0 + tx * 4);
    const float* a0 = (const float*)&v0;
    const float* a1 = (const float*)&v1;
#pragma unroll
    for (int i = 0; i < 4; ++i) {
      unsigned val = (unsigned)f2bf(a0[i]) | ((unsigned)f2bf(a1[i]) << 16);
      *(unsigned*)&lds16[(tx * 4 + i) * 66 + k] = val;
    }
  }
  __syncthreads();
#pragma unroll
  for (int p = 0; p < 2; ++p) {
    int n = (tid >> 3) + p * 32;
    int k8 = (tid & 7) * 8;
    const unsigned* l32 = (const unsigned*)&lds16[n * 66 + k8];
    uint4 o4;
    o4.x = l32[0]; o4.y = l32[1]; o4.z = l32[2]; o4.w = l32[3];
    *(uint4*)(out + (size_t)(n0 + n) * K + k0 + k8) = o4;
  }
}

// ---------------- early transpose: w_attn only ----------------
__global__ void transpose_wattn_k(const float* __restrict__ in, u16* __restrict__ out)
{
  __shared__ u16 lds16[64 * 66];
  int r = blockIdx.x;                     // 768 tiles: 48 n x 16 k
  int n0 = (r % 48) * 64, k0 = (r / 48) * 64;
  tp_body(in, out, 1024, 3072, k0, n0, lds16, threadIdx.x);
}

// ---------------- bias concat + counts init ----------------
__global__ void concat_bias_k(const float* __restrict__ exp_bf, const float* __restrict__ sh_bf,
                              const float* __restrict__ exp_bp, const float* __restrict__ sh_bp,
                              float* __restrict__ bf17, float* __restrict__ bp17,
                              int* __restrict__ counts)
{
  int i = blockIdx.x * 256 + threadIdx.x;
  if (i < 16 * 2048) bf17[i] = exp_bf[i];
  else if (i < 17 * 2048) bf17[i] = sh_bf[i - 16 * 2048];
  if (i < 16 * 1024) bp17[i] = exp_bp[i];
  else if (i < 17 * 1024) bp17[i] = sh_bp[i - 16 * 1024];
  if (blockIdx.x == 0 && threadIdx.x <= NEXP)
    counts[threadIdx.x] = (threadIdx.x == NEXP) ? NTOK : 0;
}

// ---------------- RMSNorm (1): f32 row -> bf16 ----------------
__global__ void rmsnorm_k(const float* __restrict__ x, const float* __restrict__ w,
                          u16* __restrict__ ob)
{
  int row = blockIdx.x, tid = threadIdx.x;
  const float4* xr = (const float4*)(x + (size_t)row * CDIM);
  float4 v = xr[tid];
  float ss = v.x*v.x + v.y*v.y + v.z*v.z + v.w*v.w;
  for (int d = 1; d < 64; d <<= 1) ss += __shfl_xor(ss, d);
  __shared__ float wacc[4];
  if ((tid & 63) == 0) wacc[tid >> 6] = ss;
  __syncthreads();
  float tot = wacc[0] + wacc[1] + wacc[2] + wacc[3];
  float scale = rsqrtf(tot * (1.0f / CDIM) + 1e-5f);
  float4 wv = ((const float4*)w)[tid];
  float o0 = v.x * scale * wv.x, o1 = v.y * scale * wv.y;
  float o2 = v.z * scale * wv.z, o3 = v.w * scale * wv.w;
  ushort4 ov; ov.x = f2bf(o0); ov.y = f2bf(o1); ov.z = f2bf(o2); ov.w = f2bf(o3);
  ((ushort4*)(ob + (size_t)row * CDIM))[tid] = ov;
}

// ---------------- FUSED RMSNorm2 + gate: x2 -> h2b bf16 + routing ----------------
// rmsnorm math verbatim; h2 f32 values go to LDS hrow (same values gate_k previously
// re-read from global) -> gate logic verbatim -> bit-identical routing.
__global__ void rmsnorm_gate_k(const float* __restrict__ x2, const float* __restrict__ w,
                               const float* __restrict__ gw, const float* __restrict__ gb,
                               u16* __restrict__ ob,
                               int* __restrict__ route_e, float* __restrict__ route_w,
                               int* __restrict__ counts, float* __restrict__ probs)
{
  int row = blockIdx.x, tid = threadIdx.x;
  __shared__ float hrow[CDIM];
  __shared__ float wacc[4];
  __shared__ float part[16][17];
  __shared__ float sm[16];

  // --- rmsnorm (verbatim) ---
  const float4* xr = (const float4*)(x2 + (size_t)row * CDIM);
  float4 v = xr[tid];
  float ss = v.x*v.x + v.y*v.y + v.z*v.z + v.w*v.w;
  for (int d = 1; d < 64; d <<= 1) ss += __shfl_xor(ss, d);
  if ((tid & 63) == 0) wacc[tid >> 6] = ss;
  __syncthreads();
  float tot = wacc[0] + wacc[1] + wacc[2] + wacc[3];
  float scale = rsqrtf(tot * (1.0f / CDIM) + 1e-5f);
  float4 wv = ((const float4*)w)[tid];
  float o0 = v.x * scale * wv.x, o1 = v.y * scale * wv.y;
  float o2 = v.z * scale * wv.z, o3 = v.w * scale * wv.w;
  ((float4*)hrow)[tid] = make_float4(o0, o1, o2, o3);
  ushort4 ov; ov.x = f2bf(o0); ov.y = f2bf(o1); ov.z = f2bf(o2); ov.w = f2bf(o3);
  ((ushort4*)(ob + (size_t)row * CDIM))[tid] = ov;
  __syncthreads();

  // --- gate (verbatim from gate_k) ---
  int e = tid & 15, seg = tid >> 4;
  const float4* gw4 = (const float4*)(gw + (size_t)e * CDIM + seg * 64);
  const float4* hs4 = (const float4*)(hrow + seg * 64);
  float p = 0.f;
#pragma unroll
  for (int i = 0; i < 16; ++i) {
    float4 gv = gw4[i];
    float4 hv = hs4[i];
    p += hv.x * gv.x;
    p += hv.y * gv.y;
    p += hv.z * gv.z;
    p += hv.w * gv.w;
  }
  part[e][seg] = p;
  __syncthreads();
  if (tid < 16) {
    float lg = 0.f;
    for (int s = 0; s < 16; ++s) lg += part[tid][s];
    sm[tid] = lg;
  }
  __syncthreads();
  if (tid == 0) {
    float mx = sm[0];
    for (int i = 1; i < 16; ++i) mx = fmaxf(mx, sm[i]);
    float ssum = 0.f;
    for (int i = 0; i < 16; ++i) { float pe = expf(sm[i] - mx); sm[i] = pe; ssum += pe; }
    float inv = 1.0f / ssum;
    for (int i = 0; i < 16; ++i) sm[i] *= inv;
    int i1 = -1; float b1 = -1e30f;
    for (int i = 0; i < 16; ++i) { float t = sm[i] + gb[i]; if (t > b1) { b1 = t; i1 = i; } }
    int i2 = -1; float b2 = -1e30f;
    for (int i = 0; i < 16; ++i) { if (i == i1) continue; float t = sm[i] + gb[i]; if (t > b2) { b2 = t; i2 = i; } }
    route_e[2 * row] = i1; route_e[2 * row + 1] = i2;
    route_w[2 * row] = sm[i1]; route_w[2 * row + 1] = sm[i2];
    atomicAdd(&counts[i1], 1); atomicAdd(&counts[i2], 1);
  }
  __syncthreads();
  if (tid < 16) probs[(size_t)row * 16 + tid] = sm[tid];
}

// ---------------- GEMM: C[M,N] = A[M,K](bf16) @ Bt[N,K](bf16)^T + bias ----------------
// MODE 0: f32 ; 1: f32+resid ; 2: bf16 silu ; 4: bf16 plain ;
// 5: qkv fused-v. SWZ=1 chunked relabel (uniform density only); SWZ=0 plain.
template<int MODE, int SWZ>
__global__ void __launch_bounds__(256, 4)
gemm_bt(const u16* __restrict__ A, int lda,
        const u16* __restrict__ Bt, long long bStrideZ,
        const float* __restrict__ bias, int biasStrideZ,
        void* __restrict__ Cout,
        const float* __restrict__ resid,
        int M, int N, int K,
        const int* __restrict__ counts, const int* __restrict__ offsets,
        const int* __restrict__ tokA, u16* __restrict__ vtp)
{
  int cb, rb, z;
  if (SWZ) {
    int nwg = gridDim.x * gridDim.y * gridDim.z;
    int d = (blockIdx.z * gridDim.y + blockIdx.y) * gridDim.x + blockIdx.x;
    int o = (d & 7) * (nwg >> 3) + (d >> 3);
    cb = o % gridDim.x;
    int t2 = o / gridDim.x;
    rb = t2 % gridDim.y;
    z  = t2 / gridDim.y;
  } else {
    cb = blockIdx.x; rb = blockIdx.y; z = blockIdx.z;
  }

  int mLoc = M, rowBase = 0;
  if (counts) { mLoc = counts[z]; rowBase = offsets[z]; }
  if (rb * 128 >= mLoc) return;

  const u16* Bz = Bt + (size_t)z * bStrideZ;
  const float* bz = bias + (size_t)z * biasStrideZ;

  __shared__ u16 lds_a[2][128 * 32];
  __shared__ u16 lds_b[2][128 * 32];

  int tid = threadIdx.x;
  int lane = tid & 63, wave = tid >> 6;
  int wm = wave >> 1, wn = wave & 1;
  int srow = wave * 16 + (lane >> 2);
  int skel = (lane & 3) * 8;
  int r16 = lane & 15, g8 = (lane >> 4) * 8;

  size_t arow[2];
  int ncol[2];
#pragma unroll
  for (int c = 0; c < 2; ++c) {
    int rloc = rb * 128 + c * 64 + srow;
    if (rloc >= mLoc) rloc = mLoc - 1;
    int grow = rowBase + rloc;
    arow[c] = tokA ? (size_t)tokA[grow] : (size_t)grow;
    ncol[c] = cb * 128 + c * 64 + srow;
  }

  f32x4 acc[4][4] = {};

  auto stage = [&](int kt, int buf){
    int k0 = kt * 32;
#pragma unroll
    for (int c = 0; c < 2; ++c) {
      gload_lds16(A + arow[c] * lda + k0 + skel,
                  (char*)&lds_a[buf][0] + c * 4096 + wave * 1024);
      gload_lds16(Bz + (size_t)ncol[c] * K + k0 + skel,
                  (char*)&lds_b[buf][0] + c * 4096 + wave * 1024);
    }
  };

  int nkt = K >> 5;
  stage(0, 0);
  for (int kt = 0; kt < nkt; ++kt) {
    int buf = kt & 1;
    if (kt + 1 < nkt) {
      stage(kt + 1, buf ^ 1);
      asm volatile("s_waitcnt vmcnt(4)" ::: "memory");
    } else {
      asm volatile("s_waitcnt vmcnt(0)" ::: "memory");
    }
    __builtin_amdgcn_s_barrier();
    short8 af[4], bfr[4];
#pragma unroll
    for (int i = 0; i < 4; ++i) {
      af[i]  = *(const short8*)&lds_a[buf][(wm * 64 + i * 16 + r16) * 32 + g8];
      bfr[i] = *(const short8*)&lds_b[buf][(wn * 64 + i * 16 + r16) * 32 + g8];
    }
#pragma unroll
    for (int i = 0; i < 4; ++i)
#pragma unroll
      for (int j = 0; j < 4; ++j)
        acc[i][j] = mfma16(af[i], bfr[j], acc[i][j]);
    __builtin_amdgcn_s_barrier();
  }

  // epilogue: row = (lane>>4)*4 + r, col = lane&15
#pragma unroll
  for (int i = 0; i < 4; ++i) {
    int rl0 = rb * 128 + wm * 64 + i * 16 + (lane >> 4) * 4;
#pragma unroll
    for (int j = 0; j < 4; ++j) {
      int col = cb * 128 + wn * 64 + j * 16 + r16;
      float bv = bz[col];
#pragma unroll
      for (int r = 0; r < 4; ++r) {
        int rl = rl0 + r;
        if (rl >= mLoc) continue;
        int grow = rowBase + rl;
        float v = acc[i][j][r] + bv;
        if (MODE == 0) {
          ((float*)Cout)[(size_t)grow * N + col] = v;
        } else if (MODE == 1) {
          ((float*)Cout)[(size_t)grow * N + col] = v + resid[(size_t)grow * N + col];
        } else if (MODE == 2) {
          float s = v * (1.0f / (1.0f + __expf(-v)));
          ((u16*)Cout)[(size_t)grow * N + col] = f2bf(s);
        } else if (MODE == 4) {
          ((u16*)Cout)[(size_t)grow * N + col] = f2bf(v);
        } else {
          if (col < 2048) {
            ((float*)Cout)[(size_t)grow * N + col] = v;
          } else {
            int c10 = col - 2048;
            int h = c10 >> 6, dd = c10 & 63;
            int b = grow >> 11, t = grow & 2047;
            vtp[((size_t)(b * 16 + h) * 64 + dd) * TSEQ + t] = f2bf(v);
          }
        }
      }
    }
  }
}

// ---------------- RoPE (q,k only): qkv f32 -> q,k [BH][T][D] bf16 ----------------
__global__ void rope_qk_k(const float* __restrict__ qkv,
                          u16* __restrict__ qr, u16* __restrict__ kr)
{
  int flat = blockIdx.x * 256 + threadIdx.x;
  int i = flat & 31;
  int h = (flat >> 5) & 15;
  int n = flat >> 9;
  int b = n >> 11, t = n & 2047;
  const float* row = qkv + (size_t)n * 3072;
  float2 q = *(const float2*)(row + h * 64 + 2 * i);
  float2 k = *(const float2*)(row + 1024 + h * 64 + 2 * i);
  float freq = expf(-(float)i * (2.0f / 64.0f) * 9.210340371976184f);
  float ang = (float)t * freq;
  float sn, cs;
  sincosf(ang, &sn, &cs);
  float q0 = q.x * cs - q.y * sn, q1 = q.x * sn + q.y * cs;
  float k0 = k.x * cs - k.y * sn, k1 = k.x * sn + k.y * cs;
  int bh = b * 16 + h;
  size_t qoff = ((size_t)bh * TSEQ + t) * 64 + 2 * i;
  *(unsigned*)(qr + qoff) = (unsigned)f2bf(q0) | ((unsigned)f2bf(q1) << 16);
  *(unsigned*)(kr + qoff) = (unsigned)f2bf(k0) | ((unsigned)f2bf(k1) << 16);
}

// ---------------- FUSED: flash attention (512 blocks) + weight transposes (8832 blocks) ----------------
// Attn mapping: j = u>>5 (LPT position), bh = u&31 -> all 16 blocks of one bh land on
// XCD bh%8 (u%8 = bh%8): K/V stays in one XCD's L2 (2MB/XCD) instead of 8-way replication.
__global__ void __launch_bounds__(512, 4)
attn_tp_k(const u16* __restrict__ qr, const u16* __restrict__ kr,
          const u16* __restrict__ vt, u16* __restrict__ y,
          const float* __restrict__ wProj, const float* __restrict__ shWf,
          const float* __restrict__ shWp,  const float* __restrict__ expWf,
          const float* __restrict__ expWp,
          u16* __restrict__ oProj, u16* __restrict__ oWf17, u16* __restrict__ oWp17)
{
  __shared__ union {
    struct { u16 lK[2][64 * 64]; u16 lV[2][64 * 64]; u16 plds[8][16 * 72]; } a;  // 51200 B
    u16 t[2][64 * 66];                                                            // 16896 B
  } sm;

  int u = blockIdx.x;
  if (u >= 512) {
    int tid = threadIdx.x;
    int half = tid >> 8, t256 = tid & 255;
    int t = (u - 512) * 2 + half;          // 0..17663
    const float* in; u16* out; int K, N, k0, n0;
    if (t < 8192) {                        // exp_wf
      int z = t >> 9, r = t & 511;
      in = expWf + (size_t)z * 2048 * 1024; out = oWf17 + (size_t)z * 2048 * 1024;
      K = 1024; N = 2048; n0 = (r & 31) * 64; k0 = (r >> 5) * 64;
    } else if (t < 16384) {                // exp_wp
      int z = (t - 8192) >> 9, r = (t - 8192) & 511;
      in = expWp + (size_t)z * 2048 * 1024; out = oWp17 + (size_t)z * 2048 * 1024;
      K = 2048; N = 1024; n0 = (r & 15) * 64; k0 = (r >> 4) * 64;
    } else if (t < 16896) {                // sh_wf -> slot 16
      int r = t - 16384;
      in = shWf; out = oWf17 + (size_t)16 * 2048 * 1024;
      K = 1024; N = 2048; n0 = (r & 31) * 64; k0 = (r >> 5) * 64;
    } else if (t < 17408) {                // sh_wp -> slot 16
      int r = t - 16896;
      in = shWp; out = oWp17 + (size_t)16 * 2048 * 1024;
      K = 2048; N = 1024; n0 = (r & 15) * 64; k0 = (r >> 4) * 64;
    } else {                               // w_proj
      int r = t - 17408;
      in = wProj; out = oProj; K = 1024; N = 1024; n0 = (r & 15) * 64; k0 = (r >> 4) * 64;
    }
    tp_body(in, out, K, N, k0, n0, &sm.t[half][0], t256);
    return;
  }

  // ---- attention branch (R7-exact arithmetic; bh-grouped XCD mapping) ----
  int j  = u >> 5;                         // 0..15, dispatch-order position
  int bh = u & 31;                         // all j-blocks of bh share XCD bh%8
  int b = bh >> 4, h = bh & 15;
  int qb = 15 - j;                         // LPT: heavy tiles dispatched first
  int tid = threadIdx.x;
  int wv = tid >> 6, lane = tid & 63;
  int qrow0 = qb * 128 + wv * 16;
  const u16* qbase = qr + (size_t)bh * TSEQ * 64;
  const u16* kbase = kr + (size_t)bh * TSEQ * 64;
  const u16* vbase = vt + (size_t)bh * 64 * TSEQ;

  u16* pw = &sm.a.plds[wv][0];

  int r16 = lane & 15, g = lane >> 4;

  short8 aq0 = *(const short8*)(qbase + (size_t)(qrow0 + r16) * 64 + g * 8);
  short8 aq1 = *(const short8*)(qbase + (size_t)(qrow0 + r16) * 64 + 32 + g * 8);

  int sRow = tid >> 3;
  int sColE = (((tid & 7) * 16) ^ ((sRow & 7) << 4)) >> 1;

  float m[4] = {-1e30f, -1e30f, -1e30f, -1e30f};
  float l[4] = {0.f, 0.f, 0.f, 0.f};
  f32x4 o[4] = {};

  int nt = 2 * qb + 2;

  auto stage = [&](int t, int buf){
    int kp = t * 64;
    gload_lds16(kbase + ((size_t)(kp + sRow) << 6) + sColE,
                (char*)&sm.a.lK[buf][0] + wv * 1024);
    gload_lds16(vbase + (size_t)sRow * TSEQ + kp + sColE,
                (char*)&sm.a.lV[buf][0] + wv * 1024);
  };

  auto compute = [&](int t, int buf){
    int kp = t * 64;
    f32x4 s[4];
    __builtin_amdgcn_s_setprio(1);
#pragma unroll
    for (int st = 0; st < 4; ++st) {
      int rowK = st * 16 + r16;
      int sw = (rowK & 7) << 4;
      short8 kb0 = *(const short8*)((const char*)&sm.a.lK[buf][0] + rowK * 128 + ((g * 16) ^ sw));
      short8 kb1 = *(const short8*)((const char*)&sm.a.lK[buf][0] + rowK * 128 + ((64 + g * 16) ^ sw));
      f32x4 acc = {0.f, 0.f, 0.f, 0.f};
      acc = mfma16(aq0, kb0, acc);
      acc = mfma16(aq1, kb1, acc);
      s[st] = acc;
    }
    __builtin_amdgcn_s_setprio(0);

    float sc[4];
#pragma unroll
    for (int r = 0; r < 4; ++r) {
      int qpos = qrow0 + g * 4 + r;
      float v0 = (kp + r16      <= qpos) ? s[0][r] * 0.125f : -1e30f;
      float v1 = (kp + 16 + r16 <= qpos) ? s[1][r] * 0.125f : -1e30f;
      float v2 = (kp + 32 + r16 <= qpos) ? s[2][r] * 0.125f : -1e30f;
      float v3 = (kp + 48 + r16 <= qpos) ? s[3][r] * 0.125f : -1e30f;
      float mx = fmaxf(fmaxf(v0, v1), fmaxf(v2, v3));
      for (int d = 1; d < 16; d <<= 1) mx = fmaxf(mx, __shfl_xor(mx, d));
      float mnew = fmaxf(m[r], mx);
      float e0 = __expf(v0 - mnew), e1 = __expf(v1 - mnew);
      float e2 = __expf(v2 - mnew), e3 = __expf(v3 - mnew);
      float scale = __expf(m[r] - mnew);
      float rs = (e0 + e1) + (e2 + e3);
      for (int d = 1; d < 16; d <<= 1) rs += __shfl_xor(rs, d);
      l[r] = l[r] * scale + rs;
      m[r] = mnew;
      sc[r] = scale;
      int prow = (g * 4 + r) * 72;
      pw[prow + r16]      = f2bf(e0);
      pw[prow + 16 + r16] = f2bf(e1);
      pw[prow + 32 + r16] = f2bf(e2);
      pw[prow + 48 + r16] = f2bf(e3);
    }
#pragma unroll
    for (int c = 0; c < 4; ++c) {
      f32x4 t4 = o[c];
      t4[0] *= sc[0]; t4[1] *= sc[1]; t4[2] *= sc[2]; t4[3] *= sc[3];
      o[c] = t4;
    }

    short8 pa0 = *(const short8*)&pw[r16 * 72 + g * 8];
    short8 pa1 = *(const short8*)&pw[r16 * 72 + 32 + g * 8];
    __builtin_amdgcn_s_setprio(1);
#pragma unroll
    for (int c = 0; c < 4; ++c) {
      int rowV = c * 16 + r16;
      int sw = (rowV & 7) << 4;
      short8 vb0 = *(const short8*)((const char*)&sm.a.lV[buf][0] + rowV * 128 + ((g * 16) ^ sw));
      short8 vb1 = *(const short8*)((const char*)&sm.a.lV[buf][0] + rowV * 128 + ((64 + g * 16) ^ sw));
      o[c] = mfma16(pa0, vb0, o[c]);
      o[c] = mfma16(pa1, vb1, o[c]);
    }
    __builtin_amdgcn_s_setprio(0);
  };

  stage(0, 0);
  for (int t = 0; t < nt; ++t) {
    int buf = t & 1;
    if (t + 1 < nt) {
      stage(t + 1, buf ^ 1);
      asm volatile("s_waitcnt vmcnt(2)" ::: "memory");
    } else {
      asm volatile("s_waitcnt vmcnt(0)" ::: "memory");
    }
    __builtin_amdgcn_s_barrier();
    compute(t, buf);
    __builtin_amdgcn_s_barrier();
  }

#pragma unroll
  for (int c = 0; c < 4; ++c)
#pragma unroll
    for (int r = 0; r < 4; ++r) {
      int qpos = qrow0 + g * 4 + r;
      float val = o[c][r] / l[r];
      y[((size_t)(b * TSEQ + qpos)) * CDIM + h * 64 + c * 16 + r16] = f2bf(val);
    }
}

// ---------------- routing helpers ----------------
__global__ void scan_k(const int* counts, int* offs, int* cursors){
  if (threadIdx.x == 0) {
    int acc = 0;
    for (int e = 0; e < NEXP; ++e) { offs[e] = acc; cursors[e] = acc; acc += counts[e]; }
    offs[NEXP] = acc;   // = 8192, rowBase for shared pseudo-expert
  }
}

__global__ void fill_k(const int* __restrict__ route_e, const float* __restrict__ route_w,
                       int* __restrict__ cursors, int* __restrict__ tok, float* __restrict__ tw,
                       int* __restrict__ inv)
{
  int n = blockIdx.x * 256 + threadIdx.x;
  if (n >= NTOK) return;
  for (int j = 0; j < 2; ++j) {
    int e = route_e[2 * n + j];
    int pos = atomicAdd(&cursors[e], 1);
    tok[pos] = n; tw[pos] = route_w[2 * n + j];
    inv[2 * n + j] = pos;
  }
  tok[2 * NTOK + n] = n;   // shared pseudo-expert: identity gather
}

// out[n] = x2[n] + esh[n] + e0*w0 + e1*w1   (eout bf16, downstream of routing)
__global__ void combine_k(float* __restrict__ out, const float* __restrict__ x2,
                          const u16* __restrict__ eout,
                          const int* __restrict__ inv, const float* __restrict__ tw)
{
  int n = blockIdx.x, tid = threadIdx.x;
  int p0 = inv[2 * n], p1 = inv[2 * n + 1];
  float w0 = tw[p0], w1 = tw[p1];
  float4 xr = ((const float4*)(x2 + (size_t)n * CDIM))[tid];
  ushort4 es = ((const ushort4*)(eout + (size_t)(2 * NTOK + n) * CDIM))[tid];
  float4 a;
  a.x = xr.x + bf2f(es.x);
  a.y = xr.y + bf2f(es.y);
  a.z = xr.z + bf2f(es.z);
  a.w = xr.w + bf2f(es.w);
  ushort4 e0 = ((const ushort4*)(eout + (size_t)p0 * CDIM))[tid];
  ushort4 e1 = ((const ushort4*)(eout + (size_t)p1 * CDIM))[tid];
  a.x += bf2f(e0.x) * w0 + bf2f(e1.x) * w1;
  a.y += bf2f(e0.y) * w0 + bf2f(e1.y) * w1;
  a.z += bf2f(e0.z) * w0 + bf2f(e1.z) * w1;
  a.w += bf2f(e0.w) * w0 + bf2f(e1.w) * w1;
  ((float4*)(out + (size_t)n * CDIM))[tid] = a;
}

// deterministic psum reduction + lb loss
__global__ void lb2_k(const int* __restrict__ counts, const float* __restrict__ probs,
                      float* __restrict__ out)
{
  __shared__ float part[256][16];
  int t = threadIdx.x;
  float acc[16];
#pragma unroll
  for (int e = 0; e < 16; ++e) acc[e] = 0.f;
  for (int n = t; n < NTOK; n += 256) {
    const float4* row = (const float4*)(probs + (size_t)n * 16);
    float4 a0 = row[0], a1 = row[1], a2 = row[2], a3 = row[3];
    acc[0] += a0.x; acc[1] += a0.y; acc[2]  += a0.z; acc[3]  += a0.w;
    acc[4] += a1.x; acc[5] += a1.y; acc[6]  += a1.z; acc[7]  += a1.w;
    acc[8] += a2.x; acc[9] += a2.y; acc[10] += a2.z; acc[11] += a2.w;
    acc[12] += a3.x; acc[13] += a3.y; acc[14] += a3.z; acc[15] += a3.w;
  }
#pragma unroll
  for (int e = 0; e < 16; ++e) part[t][e] = acc[e];
  __syncthreads();
  __shared__ float colsum[16];
  if (t < 16) {
    float s = 0.f;
    for (int i = 0; i < 256; ++i) s += part[i][t];
    colsum[t] = s;
  }
  __syncthreads();
  if (t == 0) {
    float accl = 0.f;
    for (int e = 0; e < NEXP; ++e) {
      float f = (float)counts[e] * (16.0f / (2.0f * (float)NTOK + 1e-6f));
      accl += f * (colsum[e] * (1.0f / (float)NTOK));
    }
    out[0] = 0.01f * accl;
  }
}

// ---------------- launch ----------------
extern "C" void kernel_launch(void* const* d_in, const int* in_sizes, int n_in,
                              void* d_out, int out_size, void* d_ws, size_t ws_size,
                              hipStream_t stream)
{
  const float* x      = (const float*)d_in[0];
  const float* ln1_w  = (const float*)d_in[1];
  const float* ln2_w  = (const float*)d_in[2];
  const float* w_attn = (const float*)d_in[3];
  const float* b_attn = (const float*)d_in[4];
  const float* w_proj = (const float*)d_in[5];
  const float* b_proj = (const float*)d_in[6];
  const float* gate_w = (const float*)d_in[7];
  const float* gate_b = (const float*)d_in[8];
  const float* exp_wf = (const float*)d_in[9];
  const float* exp_bf = (const float*)d_in[10];
  const float* exp_wp = (const float*)d_in[11];
  const float* exp_bp = (const float*)d_in[12];
  const float* sh_wf  = (const float*)d_in[13];
  const float* sh_bf  = (const float*)d_in[14];
  const float* sh_wp  = (const float*)d_in[15];
  const float* sh_bp  = (const float*)d_in[16];

  char* ws = (char*)d_ws;
  size_t off = 0;
  auto alloc = [&](size_t b){ size_t r = off; off = (off + b + 255) & ~(size_t)255; return r; };

  size_t oWAttnT = alloc(3072ull * 1024 * 2);
  size_t oWProjT = alloc(1024ull * 1024 * 2);
  size_t oExpWfT = alloc(17ull * 2048 * 1024 * 2);   // slot 16 = sh_wf
  size_t oExpWpT = alloc(17ull * 1024 * 2048 * 2);   // slot 16 = sh_wp
  size_t oX2     = alloc(4096ull * 1024 * 4);
  size_t oH2B    = alloc(4096ull * 1024 * 2);
  size_t oQKV    = alloc(4096ull * 3072 * 4);        // qkv f32 48MB; later hid17 bf16 [12288][2048]=48MB
  size_t oQR     = alloc(4096ull * 1024 * 2);        // QR+KR+VT span; later eout bf16 [12288][1024]=24MB
  size_t oKR     = alloc(4096ull * 1024 * 2);
  size_t oVT     = alloc(4096ull * 1024 * 2);
  size_t oH1B    = alloc(4096ull * 1024 * 2);        // h1; later y
  size_t oCnt    = alloc(128);
  size_t oOffs   = alloc(128);
  size_t oCurs   = alloc(128);
  size_t oRE     = alloc(8192ull * 4);
  size_t oRW     = alloc(8192ull * 4);
  size_t oTok    = alloc(12288ull * 4);
  size_t oTw     = alloc(8192ull * 4);
  size_t oInv    = alloc(8192ull * 4);
  size_t oProbs  = alloc(4096ull * 16 * 4);
  size_t oBf17   = alloc(17ull * 2048 * 4);
  size_t oBp17   = alloc(17ull * 1024 * 4);

  u16* pWAttnT = (u16*)(ws + oWAttnT);
  u16* pWProjT = (u16*)(ws + oWProjT);
  u16* pWf17   = (u16*)(ws + oExpWfT);
  u16* pWp17   = (u16*)(ws + oExpWpT);
  float* pX2   = (float*)(ws + oX2);
  u16* pH2B    = (u16*)(ws + oH2B);
  float* pQKV  = (float*)(ws + oQKV);
  u16* pHid17  = (u16*)(ws + oQKV);             // alias (qkv dead after rope)
  u16* pQR     = (u16*)(ws + oQR);
  u16* pKR     = (u16*)(ws + oKR);
  u16* pVT     = (u16*)(ws + oVT);
  u16* pH1B    = (u16*)(ws + oH1B);
  u16* pY      = (u16*)(ws + oH1B);             // alias (h1 dead after qkv gemm)
  u16* pEoutB  = (u16*)(ws + oQR);              // alias (qr/kr/vt dead), eout bf16 24MB
  int* pCnt    = (int*)(ws + oCnt);
  int* pOffs   = (int*)(ws + oOffs);
  int* pCurs   = (int*)(ws + oCurs);
  int* pRE     = (int*)(ws + oRE);
  float* pRW   = (float*)(ws + oRW);
  int* pTok    = (int*)(ws + oTok);
  float* pTw   = (float*)(ws + oTw);
  int* pInv    = (int*)(ws + oInv);
  float* pProbs= (float*)(ws + oProbs);
  float* pBf17 = (float*)(ws + oBf17);
  float* pBp17 = (float*)(ws + oBp17);

  // 1) early transpose (w_attn) + bias concat + counts init
  transpose_wattn_k<<<768, 256, 0, stream>>>(w_attn, pWAttnT);
  concat_bias_k<<<(17 * 2048 + 255) / 256, 256, 0, stream>>>(exp_bf, sh_bf, exp_bp, sh_bp,
                                                             pBf17, pBp17, pCnt);

  // 2) rmsnorm1 -> h1 bf16
  rmsnorm_k<<<NTOK, 256, 0, stream>>>(x, ln1_w, pH1B);

  // 3) qkv GEMM, MODE5: q/k cols f32 -> pQKV; v cols bf16 direct -> vt
  gemm_bt<5, 1><<<dim3(3072/128, NTOK/128, 1), 256, 0, stream>>>(
      pH1B, 1024, pWAttnT, 0, b_attn, 0, pQKV, nullptr,
      NTOK, 3072, 1024, nullptr, nullptr, nullptr, pVT);

  // 4) rope (q,k only)
  rope_qk_k<<<(NTOK * 16 * 32) / 256, 256, 0, stream>>>(pQKV, pQR, pKR);

  // 5) FUSED: causal flash attention + remaining weight transposes
  attn_tp_k<<<512 + 8832, 512, 0, stream>>>(pQR, pKR, pVT, pY,
                                            w_proj, sh_wf, sh_wp, exp_wf, exp_wp,
                                            pWProjT, pWf17, pWp17);

  // 6) x2 = x + y @ w_proj + b_proj
  gemm_bt<1, 1><<<dim3(1024/128, NTOK/128, 1), 256, 0, stream>>>(
      pY, 1024, pWProjT, 0, b_proj, 0, pX2, x,
      NTOK, 1024, 1024, nullptr, nullptr, nullptr, nullptr);

  // 7) FUSED rmsnorm2 + gate -> h2b, routing tables, probs
  rmsnorm_gate_k<<<NTOK, 256, 0, stream>>>(pX2, ln2_w, gate_w, gate_b,
                                           pH2B, pRE, pRW, pCnt, pProbs);

  // 8) routing finalize
  scan_k<<<1, 64, 0, stream>>>(pCnt, pOffs, pCurs);
  fill_k<<<NTOK/256, 256, 0, stream>>>(pRE, pRW, pCurs, pTok, pTw, pInv);
  lb2_k<<<1, 256, 0, stream>>>(pCnt, pProbs, ((float*)d_out) + (size_t)NTOK * CDIM);

  // 9) MERGED ff (experts z=0..15 ragged + shared z=16 dense), SWZ=0
  gemm_bt<2, 0><<<dim3(2048/128, NTOK/128, 17), 256, 0, stream>>>(
      pH2B, 1024, pWf17, 2048ll * 1024, pBf17, 2048, pHid17, nullptr,
      NTOK, 2048, 1024, pCnt, pOffs, pTok, nullptr);

  // 10) MERGED proj -> eout bf16 [12288][1024], SWZ=0
  gemm_bt<4, 0><<<dim3(1024/128, NTOK/128, 17), 256, 0, stream>>>(
      pHid17, 2048, pWp17, 2048ll * 1024, pBp17, 1024, pEoutB, nullptr,
      NTOK, 1024, 2048, pCnt, pOffs, nullptr, nullptr);

  // 11) d_out = x2 + esh + e0*w0 + e1*w1
  combine_k<<<NTOK, 256, 0, stream>>>((float*)d_out, pX2, pEoutB, pInv, pTw);

  (void)in_sizes; (void)n_in; (void)out_size; (void)ws_size;
}

// Round 19
// 555.539 us; speedup vs baseline: 1.2378x; 1.0639x over previous
//
#include <hip/hip_runtime.h>

// ---------------- types & helpers ----------------
typedef __bf16 bf16x8 __attribute__((ext_vector_type(8)));
typedef short  short8 __attribute__((ext_vector_type(8)));
typedef float  f32x4  __attribute__((ext_vector_type(4)));
typedef unsigned short u16;

#define NTOK 4096   // B*T
#define TSEQ 2048
#define CDIM 1024
#define NEXP 16

__device__ __forceinline__ u16 f2bf(float f){
  union { float f; unsigned u; } v; v.f = f;
  unsigned r = v.u + 0x7fffu + ((v.u >> 16) & 1u);
  return (u16)(r >> 16);
}
__device__ __forceinline__ float bf2f(u16 u){
  union { unsigned u; float f; } v; v.u = ((unsigned)u) << 16; return v.f;
}

__device__ __forceinline__ f32x4 mfma16(short8 a, short8 b, f32x4 c){
  return __builtin_amdgcn_mfma_f32_16x16x32_bf16(
      __builtin_bit_cast(bf16x8, a), __builtin_bit_cast(bf16x8, b), c, 0, 0, 0);
}

__device__ __forceinline__ void gload_lds16(const void* g, void* l){
  __builtin_amdgcn_global_load_lds((__attribute__((address_space(1))) void*)g,
                                   (__attribute__((address_space(3))) void*)l,
                                   16, 0, 0);
}

// ---------------- transpose tile body (bit-identical output) ----------------
__device__ __forceinline__ void tp_body(const float* __restrict__ in, u16* __restrict__ out,
                                        int K, int N, int k0, int n0, u16* lds16, int tid)
{
  int tx = tid & 15;
#pragma unroll
  for (int p = 0; p < 2; ++p) {
    int q = (tid >> 4) + p * 16;
    int k = 2 * q;
    float4 v0 = *(const float4*)(in + (size_t)(k0 + k)     * N + n0 + tx * 4);
    float4 v1 = *(const float4*)(in + (size_t)(k0 + k + 1) * N + n0 + tx * 4);
    const float* a0 = (const float*)&v0;
    const float* a1 = (const float*)&v1;
#pragma unroll
    for (int i = 0; i < 4; ++i) {
      unsigned val = (unsigned)f2bf(a0[i]) | ((unsigned)f2bf(a1[i]) << 16);
      *(unsigned*)&lds16[(tx * 4 + i) * 66 + k] = val;
    }
  }
  __syncthreads();
#pragma unroll
  for (int p = 0; p < 2; ++p) {
    int n = (tid >> 3) + p * 32;
    int k8 = (tid & 7) * 8;
    const unsigned* l32 = (const unsigned*)&lds16[n * 66 + k8];
    uint4 o4;
    o4.x = l32[0]; o4.y = l32[1]; o4.z = l32[2]; o4.w = l32[3];
    *(uint4*)(out + (size_t)(n0 + n) * K + k0 + k8) = o4;
  }
}

// ---------------- early transpose: w_attn only ----------------
__global__ void transpose_wattn_k(const float* __restrict__ in, u16* __restrict__ out)
{
  __shared__ u16 lds16[64 * 66];
  int r = blockIdx.x;                     // 768 tiles: 48 n x 16 k
  int n0 = (r % 48) * 64, k0 = (r / 48) * 64;
  tp_body(in, out, 1024, 3072, k0, n0, lds16, threadIdx.x);
}

// ---------------- bias concat + counts init ----------------
__global__ void concat_bias_k(const float* __restrict__ exp_bf, const float* __restrict__ sh_bf,
                              const float* __restrict__ exp_bp, const float* __restrict__ sh_bp,
                              float* __restrict__ bf17, float* __restrict__ bp17,
                              int* __restrict__ counts)
{
  int i = blockIdx.x * 256 + threadIdx.x;
  if (i < 16 * 2048) bf17[i] = exp_bf[i];
  else if (i < 17 * 2048) bf17[i] = sh_bf[i - 16 * 2048];
  if (i < 16 * 1024) bp17[i] = exp_bp[i];
  else if (i < 17 * 1024) bp17[i] = sh_bp[i - 16 * 1024];
  if (blockIdx.x == 0 && threadIdx.x <= NEXP)
    counts[threadIdx.x] = (threadIdx.x == NEXP) ? NTOK : 0;
}

// ---------------- RMSNorm (1): f32 row -> bf16 ----------------
__global__ void rmsnorm_k(const float* __restrict__ x, const float* __restrict__ w,
                          u16* __restrict__ ob)
{
  int row = blockIdx.x, tid = threadIdx.x;
  const float4* xr = (const float4*)(x + (size_t)row * CDIM);
  float4 v = xr[tid];
  float ss = v.x*v.x + v.y*v.y + v.z*v.z + v.w*v.w;
  for (int d = 1; d < 64; d <<= 1) ss += __shfl_xor(ss, d);
  __shared__ float wacc[4];
  if ((tid & 63) == 0) wacc[tid >> 6] = ss;
  __syncthreads();
  float tot = wacc[0] + wacc[1] + wacc[2] + wacc[3];
  float scale = rsqrtf(tot * (1.0f / CDIM) + 1e-5f);
  float4 wv = ((const float4*)w)[tid];
  float o0 = v.x * scale * wv.x, o1 = v.y * scale * wv.y;
  float o2 = v.z * scale * wv.z, o3 = v.w * scale * wv.w;
  ushort4 ov; ov.x = f2bf(o0); ov.y = f2bf(o1); ov.z = f2bf(o2); ov.w = f2bf(o3);
  ((ushort4*)(ob + (size_t)row * CDIM))[tid] = ov;
}

// ---------------- FUSED RMSNorm2 + gate ----------------
__global__ void rmsnorm_gate_k(const float* __restrict__ x2, const float* __restrict__ w,
                               const float* __restrict__ gw, const float* __restrict__ gb,
                               u16* __restrict__ ob,
                               int* __restrict__ route_e, float* __restrict__ route_w,
                               int* __restrict__ counts, float* __restrict__ probs)
{
  int row = blockIdx.x, tid = threadIdx.x;
  __shared__ float hrow[CDIM];
  __shared__ float wacc[4];
  __shared__ float part[16][17];
  __shared__ float sm[16];

  const float4* xr = (const float4*)(x2 + (size_t)row * CDIM);
  float4 v = xr[tid];
  float ss = v.x*v.x + v.y*v.y + v.z*v.z + v.w*v.w;
  for (int d = 1; d < 64; d <<= 1) ss += __shfl_xor(ss, d);
  if ((tid & 63) == 0) wacc[tid >> 6] = ss;
  __syncthreads();
  float tot = wacc[0] + wacc[1] + wacc[2] + wacc[3];
  float scale = rsqrtf(tot * (1.0f / CDIM) + 1e-5f);
  float4 wv = ((const float4*)w)[tid];
  float o0 = v.x * scale * wv.x, o1 = v.y * scale * wv.y;
  float o2 = v.z * scale * wv.z, o3 = v.w * scale * wv.w;
  ((float4*)hrow)[tid] = make_float4(o0, o1, o2, o3);
  ushort4 ov; ov.x = f2bf(o0); ov.y = f2bf(o1); ov.z = f2bf(o2); ov.w = f2bf(o3);
  ((ushort4*)(ob + (size_t)row * CDIM))[tid] = ov;
  __syncthreads();

  int e = tid & 15, seg = tid >> 4;
  const float4* gw4 = (const float4*)(gw + (size_t)e * CDIM + seg * 64);
  const float4* hs4 = (const float4*)(hrow + seg * 64);
  float p = 0.f;
#pragma unroll
  for (int i = 0; i < 16; ++i) {
    float4 gv = gw4[i];
    float4 hv = hs4[i];
    p += hv.x * gv.x;
    p += hv.y * gv.y;
    p += hv.z * gv.z;
    p += hv.w * gv.w;
  }
  part[e][seg] = p;
  __syncthreads();
  if (tid < 16) {
    float lg = 0.f;
    for (int s = 0; s < 16; ++s) lg += part[tid][s];
    sm[tid] = lg;
  }
  __syncthreads();
  if (tid == 0) {
    float mx = sm[0];
    for (int i = 1; i < 16; ++i) mx = fmaxf(mx, sm[i]);
    float ssum = 0.f;
    for (int i = 0; i < 16; ++i) { float pe = expf(sm[i] - mx); sm[i] = pe; ssum += pe; }
    float inv = 1.0f / ssum;
    for (int i = 0; i < 16; ++i) sm[i] *= inv;
    int i1 = -1; float b1 = -1e30f;
    for (int i = 0; i < 16; ++i) { float t = sm[i] + gb[i]; if (t > b1) { b1 = t; i1 = i; } }
    int i2 = -1; float b2 = -1e30f;
    for (int i = 0; i < 16; ++i) { if (i == i1) continue; float t = sm[i] + gb[i]; if (t > b2) { b2 = t; i2 = i; } }
    route_e[2 * row] = i1; route_e[2 * row + 1] = i2;
    route_w[2 * row] = sm[i1]; route_w[2 * row + 1] = sm[i2];
    atomicAdd(&counts[i1], 1); atomicAdd(&counts[i2], 1);
  }
  __syncthreads();
  if (tid < 16) probs[(size_t)row * 16 + tid] = sm[tid];
}

// ---------------- GEMM template (qkv MODE5, proj MODE1, proj17 MODE4) ----------------
template<int MODE, int SWZ>
__global__ void __launch_bounds__(256, 4)
gemm_bt(const u16* __restrict__ A, int lda,
        const u16* __restrict__ Bt, long long bStrideZ,
        const float* __restrict__ bias, int biasStrideZ,
        void* __restrict__ Cout,
        const float* __restrict__ resid,
        int M, int N, int K,
        const int* __restrict__ counts, const int* __restrict__ offsets,
        const int* __restrict__ tokA, u16* __restrict__ vtp)
{
  int cb, rb, z;
  if (SWZ) {
    int nwg = gridDim.x * gridDim.y * gridDim.z;
    int d = (blockIdx.z * gridDim.y + blockIdx.y) * gridDim.x + blockIdx.x;
    int o = (d & 7) * (nwg >> 3) + (d >> 3);
    cb = o % gridDim.x;
    int t2 = o / gridDim.x;
    rb = t2 % gridDim.y;
    z  = t2 / gridDim.y;
  } else {
    cb = blockIdx.x; rb = blockIdx.y; z = blockIdx.z;
  }

  int mLoc = M, rowBase = 0;
  if (counts) { mLoc = counts[z]; rowBase = offsets[z]; }
  if (rb * 128 >= mLoc) return;

  const u16* Bz = Bt + (size_t)z * bStrideZ;
  const float* bz = bias + (size_t)z * biasStrideZ;

  __shared__ u16 lds_a[2][128 * 32];
  __shared__ u16 lds_b[2][128 * 32];

  int tid = threadIdx.x;
  int lane = tid & 63, wave = tid >> 6;
  int wm = wave >> 1, wn = wave & 1;
  int srow = wave * 16 + (lane >> 2);
  int skel = (lane & 3) * 8;
  int r16 = lane & 15, g8 = (lane >> 4) * 8;

  size_t arow[2];
  int ncol[2];
#pragma unroll
  for (int c = 0; c < 2; ++c) {
    int rloc = rb * 128 + c * 64 + srow;
    if (rloc >= mLoc) rloc = mLoc - 1;
    int grow = rowBase + rloc;
    arow[c] = tokA ? (size_t)tokA[grow] : (size_t)grow;
    ncol[c] = cb * 128 + c * 64 + srow;
  }

  f32x4 acc[4][4] = {};

  auto stage = [&](int kt, int buf){
    int k0 = kt * 32;
#pragma unroll
    for (int c = 0; c < 2; ++c) {
      gload_lds16(A + arow[c] * lda + k0 + skel,
                  (char*)&lds_a[buf][0] + c * 4096 + wave * 1024);
      gload_lds16(Bz + (size_t)ncol[c] * K + k0 + skel,
                  (char*)&lds_b[buf][0] + c * 4096 + wave * 1024);
    }
  };

  int nkt = K >> 5;
  stage(0, 0);
  for (int kt = 0; kt < nkt; ++kt) {
    int buf = kt & 1;
    if (kt + 1 < nkt) {
      stage(kt + 1, buf ^ 1);
      asm volatile("s_waitcnt vmcnt(4)" ::: "memory");
    } else {
      asm volatile("s_waitcnt vmcnt(0)" ::: "memory");
    }
    __builtin_amdgcn_s_barrier();
    short8 af[4], bfr[4];
#pragma unroll
    for (int i = 0; i < 4; ++i) {
      af[i]  = *(const short8*)&lds_a[buf][(wm * 64 + i * 16 + r16) * 32 + g8];
      bfr[i] = *(const short8*)&lds_b[buf][(wn * 64 + i * 16 + r16) * 32 + g8];
    }
#pragma unroll
    for (int i = 0; i < 4; ++i)
#pragma unroll
      for (int j = 0; j < 4; ++j)
        acc[i][j] = mfma16(af[i], bfr[j], acc[i][j]);
    __builtin_amdgcn_s_barrier();
  }

#pragma unroll
  for (int i = 0; i < 4; ++i) {
    int rl0 = rb * 128 + wm * 64 + i * 16 + (lane >> 4) * 4;
#pragma unroll
    for (int j = 0; j < 4; ++j) {
      int col = cb * 128 + wn * 64 + j * 16 + r16;
      float bv = bz[col];
#pragma unroll
      for (int r = 0; r < 4; ++r) {
        int rl = rl0 + r;
        if (rl >= mLoc) continue;
        int grow = rowBase + rl;
        float v = acc[i][j][r] + bv;
        if (MODE == 0) {
          ((float*)Cout)[(size_t)grow * N + col] = v;
        } else if (MODE == 1) {
          ((float*)Cout)[(size_t)grow * N + col] = v + resid[(size_t)grow * N + col];
        } else if (MODE == 2) {
          float s = v * (1.0f / (1.0f + __expf(-v)));
          ((u16*)Cout)[(size_t)grow * N + col] = f2bf(s);
        } else if (MODE == 4) {
          ((u16*)Cout)[(size_t)grow * N + col] = f2bf(v);
        } else {
          if (col < 2048) {
            ((float*)Cout)[(size_t)grow * N + col] = v;
          } else {
            int c10 = col - 2048;
            int h = c10 >> 6, dd = c10 & 63;
            int b = grow >> 11, t = grow & 2047;
            vtp[((size_t)(b * 16 + h) * 64 + dd) * TSEQ + t] = f2bf(v);
          }
        }
      }
    }
  }
}

// ---------------- FUSED: merged-ff GEMM (8704 blocks) + exp_wp transpose (8192 blocks) ----------------
// GEMM part = gemm_bt<2,0> body verbatim (MODE2 silu bf16, A gathered via tok).
// Transpose part = tp_body bits (exp_wp -> wp17 slots 0..15). Independent outputs.
__global__ void __launch_bounds__(256, 4)
ff_tp_k(const u16* __restrict__ A, const u16* __restrict__ Wf17,
        const float* __restrict__ bf17, u16* __restrict__ hid17,
        const int* __restrict__ counts, const int* __restrict__ offsets,
        const int* __restrict__ tokA,
        const float* __restrict__ expWp, u16* __restrict__ oWp17)
{
  __shared__ union {
    struct { u16 a[2][128 * 32]; u16 b[2][128 * 32]; } g;   // 32768 B
    u16 t[64 * 66];                                          // 8448 B
  } sm;

  int u = blockIdx.x;
  if (u >= 8704) {
    int t = u - 8704;                      // 0..8191: exp_wp tiles
    int z = t >> 9, r = t & 511;
    tp_body(expWp + (size_t)z * 2048 * 1024, oWp17 + (size_t)z * 2048 * 1024,
            2048, 1024, (r >> 4) * 64, (r & 15) * 64, sm.t, threadIdx.x);
    return;
  }

  const int N = 2048, K = 1024, lda = 1024;
  int cb = u & 15, t2 = u >> 4;
  int rb = t2 & 31, z = t2 >> 5;           // z 0..16

  int mLoc = counts[z], rowBase = offsets[z];
  if (rb * 128 >= mLoc) return;

  const u16* Bz = Wf17 + (size_t)z * 2048 * 1024;
  const float* bz = bf17 + (size_t)z * 2048;

  int tid = threadIdx.x;
  int lane = tid & 63, wave = tid >> 6;
  int wm = wave >> 1, wn = wave & 1;
  int srow = wave * 16 + (lane >> 2);
  int skel = (lane & 3) * 8;
  int r16 = lane & 15, g8 = (lane >> 4) * 8;

  size_t arow[2];
  int ncol[2];
#pragma unroll
  for (int c = 0; c < 2; ++c) {
    int rloc = rb * 128 + c * 64 + srow;
    if (rloc >= mLoc) rloc = mLoc - 1;
    int grow = rowBase + rloc;
    arow[c] = (size_t)tokA[grow];
    ncol[c] = cb * 128 + c * 64 + srow;
  }

  f32x4 acc[4][4] = {};

  auto stage = [&](int kt, int buf){
    int k0 = kt * 32;
#pragma unroll
    for (int c = 0; c < 2; ++c) {
      gload_lds16(A + arow[c] * lda + k0 + skel,
                  (char*)&sm.g.a[buf][0] + c * 4096 + wave * 1024);
      gload_lds16(Bz + (size_t)ncol[c] * K + k0 + skel,
                  (char*)&sm.g.b[buf][0] + c * 4096 + wave * 1024);
    }
  };

  int nkt = K >> 5;
  stage(0, 0);
  for (int kt = 0; kt < nkt; ++kt) {
    int buf = kt & 1;
    if (kt + 1 < nkt) {
      stage(kt + 1, buf ^ 1);
      asm volatile("s_waitcnt vmcnt(4)" ::: "memory");
    } else {
      asm volatile("s_waitcnt vmcnt(0)" ::: "memory");
    }
    __builtin_amdgcn_s_barrier();
    short8 af[4], bfr[4];
#pragma unroll
    for (int i = 0; i < 4; ++i) {
      af[i]  = *(const short8*)&sm.g.a[buf][(wm * 64 + i * 16 + r16) * 32 + g8];
      bfr[i] = *(const short8*)&sm.g.b[buf][(wn * 64 + i * 16 + r16) * 32 + g8];
    }
#pragma unroll
    for (int i = 0; i < 4; ++i)
#pragma unroll
      for (int j = 0; j < 4; ++j)
        acc[i][j] = mfma16(af[i], bfr[j], acc[i][j]);
    __builtin_amdgcn_s_barrier();
  }

#pragma unroll
  for (int i = 0; i < 4; ++i) {
    int rl0 = rb * 128 + wm * 64 + i * 16 + (lane >> 4) * 4;
#pragma unroll
    for (int j = 0; j < 4; ++j) {
      int col = cb * 128 + wn * 64 + j * 16 + r16;
      float bv = bz[col];
#pragma unroll
      for (int r = 0; r < 4; ++r) {
        int rl = rl0 + r;
        if (rl >= mLoc) continue;
        int grow = rowBase + rl;
        float v = acc[i][j][r] + bv;
        float s = v * (1.0f / (1.0f + __expf(-v)));
        hid17[(size_t)grow * N + col] = f2bf(s);
      }
    }
  }
}

// ---------------- FUSED: flash attention (512) + wf/sh/proj transposes (4736) ----------------
__global__ void __launch_bounds__(512, 4)
attn_tp_k(const u16* __restrict__ qr, const u16* __restrict__ kr,
          const u16* __restrict__ vt, u16* __restrict__ y,
          const float* __restrict__ wProj, const float* __restrict__ shWf,
          const float* __restrict__ shWp,  const float* __restrict__ expWf,
          u16* __restrict__ oProj, u16* __restrict__ oWf17, u16* __restrict__ oWp17)
{
  __shared__ union {
    struct { u16 lK[2][64 * 64]; u16 lV[2][64 * 64]; u16 plds[8][16 * 72]; } a;  // 51200 B
    u16 t[2][64 * 66];                                                            // 16896 B
  } sm;

  int u = blockIdx.x;
  if (u >= 512) {
    int tid = threadIdx.x;
    int half = tid >> 8, t256 = tid & 255;
    int t = (u - 512) * 2 + half;          // 0..9471
    const float* in; u16* out; int K, N, k0, n0;
    if (t < 8192) {                        // exp_wf
      int z = t >> 9, r = t & 511;
      in = expWf + (size_t)z * 2048 * 1024; out = oWf17 + (size_t)z * 2048 * 1024;
      K = 1024; N = 2048; n0 = (r & 31) * 64; k0 = (r >> 5) * 64;
    } else if (t < 8704) {                 // sh_wf -> slot 16
      int r = t - 8192;
      in = shWf; out = oWf17 + (size_t)16 * 2048 * 1024;
      K = 1024; N = 2048; n0 = (r & 31) * 64; k0 = (r >> 5) * 64;
    } else if (t < 9216) {                 // sh_wp -> slot 16
      int r = t - 8704;
      in = shWp; out = oWp17 + (size_t)16 * 2048 * 1024;
      K = 2048; N = 1024; n0 = (r & 15) * 64; k0 = (r >> 4) * 64;
    } else {                               // w_proj (256 tiles)
      int r = t - 9216;
      in = wProj; out = oProj; K = 1024; N = 1024; n0 = (r & 15) * 64; k0 = (r >> 4) * 64;
    }
    tp_body(in, out, K, N, k0, n0, &sm.t[half][0], t256);
    return;
  }

  // ---- attention branch (R7-exact arithmetic; bh-grouped XCD mapping) ----
  int j  = u >> 5;
  int bh = u & 31;
  int b = bh >> 4, h = bh & 15;
  int qb = 15 - j;                         // LPT
  int tid = threadIdx.x;
  int wv = tid >> 6, lane = tid & 63;
  int qrow0 = qb * 128 + wv * 16;
  const u16* qbase = qr + (size_t)bh * TSEQ * 64;
  const u16* kbase = kr + (size_t)bh * TSEQ * 64;
  const u16* vbase = vt + (size_t)bh * 64 * TSEQ;

  u16* pw = &sm.a.plds[wv][0];

  int r16 = lane & 15, g = lane >> 4;

  short8 aq0 = *(const short8*)(qbase + (size_t)(qrow0 + r16) * 64 + g * 8);
  short8 aq1 = *(const short8*)(qbase + (size_t)(qrow0 + r16) * 64 + 32 + g * 8);

  int sRow = tid >> 3;
  int sColE = (((tid & 7) * 16) ^ ((sRow & 7) << 4)) >> 1;

  float m[4] = {-1e30f, -1e30f, -1e30f, -1e30f};
  float l[4] = {0.f, 0.f, 0.f, 0.f};
  f32x4 o[4] = {};

  int nt = 2 * qb + 2;

  auto stage = [&](int t, int buf){
    int kp = t * 64;
    gload_lds16(kbase + ((size_t)(kp + sRow) << 6) + sColE,
                (char*)&sm.a.lK[buf][0] + wv * 1024);
    gload_lds16(vbase + (size_t)sRow * TSEQ + kp + sColE,
                (char*)&sm.a.lV[buf][0] + wv * 1024);
  };

  auto compute = [&](int t, int buf){
    int kp = t * 64;
    f32x4 s[4];
    __builtin_amdgcn_s_setprio(1);
#pragma unroll
    for (int st = 0; st < 4; ++st) {
      int rowK = st * 16 + r16;
      int sw = (rowK & 7) << 4;
      short8 kb0 = *(const short8*)((const char*)&sm.a.lK[buf][0] + rowK * 128 + ((g * 16) ^ sw));
      short8 kb1 = *(const short8*)((const char*)&sm.a.lK[buf][0] + rowK * 128 + ((64 + g * 16) ^ sw));
      f32x4 acc = {0.f, 0.f, 0.f, 0.f};
      acc = mfma16(aq0, kb0, acc);
      acc = mfma16(aq1, kb1, acc);
      s[st] = acc;
    }
    __builtin_amdgcn_s_setprio(0);

    float sc[4];
#pragma unroll
    for (int r = 0; r < 4; ++r) {
      int qpos = qrow0 + g * 4 + r;
      float v0 = (kp + r16      <= qpos) ? s[0][r] * 0.125f : -1e30f;
      float v1 = (kp + 16 + r16 <= qpos) ? s[1][r] * 0.125f : -1e30f;
      float v2 = (kp + 32 + r16 <= qpos) ? s[2][r] * 0.125f : -1e30f;
      float v3 = (kp + 48 + r16 <= qpos) ? s[3][r] * 0.125f : -1e30f;
      float mx = fmaxf(fmaxf(v0, v1), fmaxf(v2, v3));
      for (int d = 1; d < 16; d <<= 1) mx = fmaxf(mx, __shfl_xor(mx, d));
      float mnew = fmaxf(m[r], mx);
      float e0 = __expf(v0 - mnew), e1 = __expf(v1 - mnew);
      float e2 = __expf(v2 - mnew), e3 = __expf(v3 - mnew);
      float scale = __expf(m[r] - mnew);
      float rs = (e0 + e1) + (e2 + e3);
      for (int d = 1; d < 16; d <<= 1) rs += __shfl_xor(rs, d);
      l[r] = l[r] * scale + rs;
      m[r] = mnew;
      sc[r] = scale;
      int prow = (g * 4 + r) * 72;
      pw[prow + r16]      = f2bf(e0);
      pw[prow + 16 + r16] = f2bf(e1);
      pw[prow + 32 + r16] = f2bf(e2);
      pw[prow + 48 + r16] = f2bf(e3);
    }
#pragma unroll
    for (int c = 0; c < 4; ++c) {
      f32x4 t4 = o[c];
      t4[0] *= sc[0]; t4[1] *= sc[1]; t4[2] *= sc[2]; t4[3] *= sc[3];
      o[c] = t4;
    }

    short8 pa0 = *(const short8*)&pw[r16 * 72 + g * 8];
    short8 pa1 = *(const short8*)&pw[r16 * 72 + 32 + g * 8];
    __builtin_amdgcn_s_setprio(1);
#pragma unroll
    for (int c = 0; c < 4; ++c) {
      int rowV = c * 16 + r16;
      int sw = (rowV & 7) << 4;
      short8 vb0 = *(const short8*)((const char*)&sm.a.lV[buf][0] + rowV * 128 + ((g * 16) ^ sw));
      short8 vb1 = *(const short8*)((const char*)&sm.a.lV[buf][0] + rowV * 128 + ((64 + g * 16) ^ sw));
      o[c] = mfma16(pa0, vb0, o[c]);
      o[c] = mfma16(pa1, vb1, o[c]);
    }
    __builtin_amdgcn_s_setprio(0);
  };

  stage(0, 0);
  for (int t = 0; t < nt; ++t) {
    int buf = t & 1;
    if (t + 1 < nt) {
      stage(t + 1, buf ^ 1);
      asm volatile("s_waitcnt vmcnt(2)" ::: "memory");
    } else {
      asm volatile("s_waitcnt vmcnt(0)" ::: "memory");
    }
    __builtin_amdgcn_s_barrier();
    compute(t, buf);
    __builtin_amdgcn_s_barrier();
  }

#pragma unroll
  for (int c = 0; c < 4; ++c)
#pragma unroll
    for (int r = 0; r < 4; ++r) {
      int qpos = qrow0 + g * 4 + r;
      float val = o[c][r] / l[r];
      y[((size_t)(b * TSEQ + qpos)) * CDIM + h * 64 + c * 16 + r16] = f2bf(val);
    }
}

// ---------------- RoPE (q,k only) ----------------
__global__ void rope_qk_k(const float* __restrict__ qkv,
                          u16* __restrict__ qr, u16* __restrict__ kr)
{
  int flat = blockIdx.x * 256 + threadIdx.x;
  int i = flat & 31;
  int h = (flat >> 5) & 15;
  int n = flat >> 9;
  int b = n >> 11, t = n & 2047;
  const float* row = qkv + (size_t)n * 3072;
  float2 q = *(const float2*)(row + h * 64 + 2 * i);
  float2 k = *(const float2*)(row + 1024 + h * 64 + 2 * i);
  float freq = expf(-(float)i * (2.0f / 64.0f) * 9.210340371976184f);
  float ang = (float)t * freq;
  float sn, cs;
  sincosf(ang, &sn, &cs);
  float q0 = q.x * cs - q.y * sn, q1 = q.x * sn + q.y * cs;
  float k0 = k.x * cs - k.y * sn, k1 = k.x * sn + k.y * cs;
  int bh = b * 16 + h;
  size_t qoff = ((size_t)bh * TSEQ + t) * 64 + 2 * i;
  *(unsigned*)(qr + qoff) = (unsigned)f2bf(q0) | ((unsigned)f2bf(q1) << 16);
  *(unsigned*)(kr + qoff) = (unsigned)f2bf(k0) | ((unsigned)f2bf(k1) << 16);
}

// ---------------- routing finalize: scan + fill + lb loss in one block ----------------
// Fill order within an expert differs from the multi-block version (LDS atomics) but
// pos assignment is a bijection and each output row depends only on its own A-row ->
// final combined values bit-identical.
__global__ void route_fin_k(const int* __restrict__ route_e, const float* __restrict__ route_w,
                            const int* __restrict__ counts, int* __restrict__ offs,
                            int* __restrict__ tok, float* __restrict__ tw, int* __restrict__ inv,
                            const float* __restrict__ probs, float* __restrict__ loss_out)
{
  __shared__ int curs[16];
  __shared__ float part[256][16];
  __shared__ float colsum[16];
  int tid = threadIdx.x;
  if (tid == 0) {
    int acc = 0;
    for (int e = 0; e < NEXP; ++e) { offs[e] = acc; curs[e] = acc; acc += counts[e]; }
    offs[NEXP] = acc;
  }
  __syncthreads();
  for (int n = tid; n < NTOK; n += 1024) {
    for (int j = 0; j < 2; ++j) {
      int e = route_e[2 * n + j];
      int pos = atomicAdd(&curs[e], 1);
      tok[pos] = n; tw[pos] = route_w[2 * n + j];
      inv[2 * n + j] = pos;
    }
    tok[2 * NTOK + n] = n;
  }
  __syncthreads();
  if (tid < 256) {
    float acc[16];
#pragma unroll
    for (int e = 0; e < 16; ++e) acc[e] = 0.f;
    for (int n = tid; n < NTOK; n += 256) {
      const float4* row = (const float4*)(probs + (size_t)n * 16);
      float4 a0 = row[0], a1 = row[1], a2 = row[2], a3 = row[3];
      acc[0] += a0.x; acc[1] += a0.y; acc[2]  += a0.z; acc[3]  += a0.w;
      acc[4] += a1.x; acc[5] += a1.y; acc[6]  += a1.z; acc[7]  += a1.w;
      acc[8] += a2.x; acc[9] += a2.y; acc[10] += a2.z; acc[11] += a2.w;
      acc[12] += a3.x; acc[13] += a3.y; acc[14] += a3.z; acc[15] += a3.w;
    }
#pragma unroll
    for (int e = 0; e < 16; ++e) part[tid][e] = acc[e];
  }
  __syncthreads();
  if (tid < 16) {
    float s = 0.f;
    for (int i = 0; i < 256; ++i) s += part[i][tid];
    colsum[tid] = s;
  }
  __syncthreads();
  if (tid == 0) {
    float accl = 0.f;
    for (int e = 0; e < NEXP; ++e) {
      float f = (float)counts[e] * (16.0f / (2.0f * (float)NTOK + 1e-6f));
      accl += f * (colsum[e] * (1.0f / (float)NTOK));
    }
    loss_out[0] = 0.01f * accl;
  }
}

// out[n] = x2[n] + esh[n] + e0*w0 + e1*w1   (eout bf16, downstream of routing)
__global__ void combine_k(float* __restrict__ out, const float* __restrict__ x2,
                          const u16* __restrict__ eout,
                          const int* __restrict__ inv, const float* __restrict__ tw)
{
  int n = blockIdx.x, tid = threadIdx.x;
  int p0 = inv[2 * n], p1 = inv[2 * n + 1];
  float w0 = tw[p0], w1 = tw[p1];
  float4 xr = ((const float4*)(x2 + (size_t)n * CDIM))[tid];
  ushort4 es = ((const ushort4*)(eout + (size_t)(2 * NTOK + n) * CDIM))[tid];
  float4 a;
  a.x = xr.x + bf2f(es.x);
  a.y = xr.y + bf2f(es.y);
  a.z = xr.z + bf2f(es.z);
  a.w = xr.w + bf2f(es.w);
  ushort4 e0 = ((const ushort4*)(eout + (size_t)p0 * CDIM))[tid];
  ushort4 e1 = ((const ushort4*)(eout + (size_t)p1 * CDIM))[tid];
  a.x += bf2f(e0.x) * w0 + bf2f(e1.x) * w1;
  a.y += bf2f(e0.y) * w0 + bf2f(e1.y) * w1;
  a.z += bf2f(e0.z) * w0 + bf2f(e1.z) * w1;
  a.w += bf2f(e0.w) * w0 + bf2f(e1.w) * w1;
  ((float4*)(out + (size_t)n * CDIM))[tid] = a;
}

// ---------------- launch ----------------
extern "C" void kernel_launch(void* const* d_in, const int* in_sizes, int n_in,
                              void* d_out, int out_size, void* d_ws, size_t ws_size,
                              hipStream_t stream)
{
  const float* x      = (const float*)d_in[0];
  const float* ln1_w  = (const float*)d_in[1];
  const float* ln2_w  = (const float*)d_in[2];
  const float* w_attn = (const float*)d_in[3];
  const float* b_attn = (const float*)d_in[4];
  const float* w_proj = (const float*)d_in[5];
  const float* b_proj = (const float*)d_in[6];
  const float* gate_w = (const float*)d_in[7];
  const float* gate_b = (const float*)d_in[8];
  const float* exp_wf = (const float*)d_in[9];
  const float* exp_bf = (const float*)d_in[10];
  const float* exp_wp = (const float*)d_in[11];
  const float* exp_bp = (const float*)d_in[12];
  const float* sh_wf  = (const float*)d_in[13];
  const float* sh_bf  = (const float*)d_in[14];
  const float* sh_wp  = (const float*)d_in[15];
  const float* sh_bp  = (const float*)d_in[16];

  char* ws = (char*)d_ws;
  size_t off = 0;
  auto alloc = [&](size_t b){ size_t r = off; off = (off + b + 255) & ~(size_t)255; return r; };

  size_t oWAttnT = alloc(3072ull * 1024 * 2);
  size_t oWProjT = alloc(1024ull * 1024 * 2);
  size_t oExpWfT = alloc(17ull * 2048 * 1024 * 2);   // slot 16 = sh_wf
  size_t oExpWpT = alloc(17ull * 1024 * 2048 * 2);   // slot 16 = sh_wp
  size_t oX2     = alloc(4096ull * 1024 * 4);
  size_t oH2B    = alloc(4096ull * 1024 * 2);
  size_t oQKV    = alloc(4096ull * 3072 * 4);        // qkv f32 48MB; later hid17 bf16
  size_t oQR     = alloc(4096ull * 1024 * 2);        // later eout bf16 [12288][1024]=24MB
  size_t oKR     = alloc(4096ull * 1024 * 2);
  size_t oVT     = alloc(4096ull * 1024 * 2);
  size_t oH1B    = alloc(4096ull * 1024 * 2);        // h1; later y
  size_t oCnt    = alloc(128);
  size_t oOffs   = alloc(128);
  size_t oRE     = alloc(8192ull * 4);
  size_t oRW     = alloc(8192ull * 4);
  size_t oTok    = alloc(12288ull * 4);
  size_t oTw     = alloc(8192ull * 4);
  size_t oInv    = alloc(8192ull * 4);
  size_t oProbs  = alloc(4096ull * 16 * 4);
  size_t oBf17   = alloc(17ull * 2048 * 4);
  size_t oBp17   = alloc(17ull * 1024 * 4);

  u16* pWAttnT = (u16*)(ws + oWAttnT);
  u16* pWProjT = (u16*)(ws + oWProjT);
  u16* pWf17   = (u16*)(ws + oExpWfT);
  u16* pWp17   = (u16*)(ws + oExpWpT);
  float* pX2   = (float*)(ws + oX2);
  u16* pH2B    = (u16*)(ws + oH2B);
  float* pQKV  = (float*)(ws + oQKV);
  u16* pHid17  = (u16*)(ws + oQKV);             // alias (qkv dead after rope)
  u16* pQR     = (u16*)(ws + oQR);
  u16* pKR     = (u16*)(ws + oKR);
  u16* pVT     = (u16*)(ws + oVT);
  u16* pH1B    = (u16*)(ws + oH1B);
  u16* pY      = (u16*)(ws + oH1B);             // alias (h1 dead after qkv gemm)
  u16* pEoutB  = (u16*)(ws + oQR);              // alias (qr/kr/vt dead), eout bf16 24MB
  int* pCnt    = (int*)(ws + oCnt);
  int* pOffs   = (int*)(ws + oOffs);
  int* pRE     = (int*)(ws + oRE);
  float* pRW   = (float*)(ws + oRW);
  int* pTok    = (int*)(ws + oTok);
  float* pTw   = (float*)(ws + oTw);
  int* pInv    = (int*)(ws + oInv);
  float* pProbs= (float*)(ws + oProbs);
  float* pBf17 = (float*)(ws + oBf17);
  float* pBp17 = (float*)(ws + oBp17);

  // 1) early transpose (w_attn) + bias concat + counts init
  transpose_wattn_k<<<768, 256, 0, stream>>>(w_attn, pWAttnT);
  concat_bias_k<<<(17 * 2048 + 255) / 256, 256, 0, stream>>>(exp_bf, sh_bf, exp_bp, sh_bp,
                                                             pBf17, pBp17, pCnt);

  // 2) rmsnorm1 -> h1 bf16
  rmsnorm_k<<<NTOK, 256, 0, stream>>>(x, ln1_w, pH1B);

  // 3) qkv GEMM, MODE5: q/k cols f32 -> pQKV; v cols bf16 direct -> vt
  gemm_bt<5, 1><<<dim3(3072/128, NTOK/128, 1), 256, 0, stream>>>(
      pH1B, 1024, pWAttnT, 0, b_attn, 0, pQKV, nullptr,
      NTOK, 3072, 1024, nullptr, nullptr, nullptr, pVT);

  // 4) rope (q,k only)
  rope_qk_k<<<(NTOK * 16 * 32) / 256, 256, 0, stream>>>(pQKV, pQR, pKR);

  // 5) FUSED: flash attention + wf/sh/proj transposes
  attn_tp_k<<<512 + 4736, 512, 0, stream>>>(pQR, pKR, pVT, pY,
                                            w_proj, sh_wf, sh_wp, exp_wf,
                                            pWProjT, pWf17, pWp17);

  // 6) x2 = x + y @ w_proj + b_proj
  gemm_bt<1, 1><<<dim3(1024/128, NTOK/128, 1), 256, 0, stream>>>(
      pY, 1024, pWProjT, 0, b_proj, 0, pX2, x,
      NTOK, 1024, 1024, nullptr, nullptr, nullptr, nullptr);

  // 7) FUSED rmsnorm2 + gate
  rmsnorm_gate_k<<<NTOK, 256, 0, stream>>>(pX2, ln2_w, gate_w, gate_b,
                                           pH2B, pRE, pRW, pCnt, pProbs);

  // 8) routing finalize (scan + fill + lb loss)
  route_fin_k<<<1, 1024, 0, stream>>>(pRE, pRW, pCnt, pOffs, pTok, pTw, pInv,
                                      pProbs, ((float*)d_out) + (size_t)NTOK * CDIM);

  // 9) FUSED: merged ff GEMM (17 slices) + exp_wp transpose
  ff_tp_k<<<8704 + 8192, 256, 0, stream>>>(pH2B, pWf17, pBf17, pHid17,
                                           pCnt, pOffs, pTok, exp_wp, pWp17);

  // 10) MERGED proj -> eout bf16 [12288][1024], SWZ=0
  gemm_bt<4, 0><<<dim3(1024/128, NTOK/128, 17), 256, 0, stream>>>(
      pHid17, 2048, pWp17, 2048ll * 1024, pBp17, 1024, pEoutB, nullptr,
      NTOK, 1024, 2048, pCnt, pOffs, nullptr, nullptr);

  // 11) d_out = x2 + esh + e0*w0 + e1*w1
  combine_k<<<NTOK, 256, 0, stream>>>((float*)d_out, pX2, pEoutB, pInv, pTw);

  (void)in_sizes; (void)n_in; (void)out_size; (void)ws_size;
}